// Round 11
// baseline (196.257 us; speedup 1.0000x reference)
//
#include <hip/hip_runtime.h>
#include <cstdint>

// MixedAttention: attention (8 heads) + trittention (4 heads, cubic scores), T=192, DIM=512.
// Round 10: (1) exp->exp2 fold (log2e into tritt a-quant and attn q-scale; exp2f = bare
// v_exp_f32, kills one v_mul per E element); (2) zgemm d-split 48->96 blocks; (3) epilogue
// M-split 96->192 blocks. tritt structure untouched (r4 optimum; r6-r8 showed any geometry
// or codegen perturbation loses 10-50 us).

#define B_   4
#define T_   192
#define DIM_ 512
#define AH   8
#define CH   4

typedef unsigned short u16;
typedef unsigned int   u32;
typedef __attribute__((ext_vector_type(8))) short short8;
typedef __attribute__((ext_vector_type(4))) float floatx4;
typedef __attribute__((ext_vector_type(4))) int intx4;
typedef __attribute__((ext_vector_type(2))) float f32x2;

union Frag { intx4 i; short8 s; };

__device__ __forceinline__ floatx4 mfma16(Frag a, Frag b, floatx4 c) {
    return __builtin_amdgcn_mfma_f32_16x16x32_bf16(a.s, b.s, c, 0, 0, 0);
}

__device__ __forceinline__ float wave_reduce_sum(float v) {
#pragma unroll
    for (int off = 32; off >= 1; off >>= 1)
        v += __shfl_xor(v, off, 64);
    return v;
}

__device__ __forceinline__ u32 pack_rne(float x, float y) {
    u32 ux = __float_as_uint(x);
    u32 uy = __float_as_uint(y);
    ux += 0x7fffu + ((ux >> 16) & 1u);
    uy += 0x7fffu + ((uy >> 16) & 1u);
    return (ux >> 16) | (uy & 0xffff0000u);
}
__device__ __forceinline__ u16 bf16_rne(float x) {
    u32 u = __float_as_uint(x);
    u += 0x7fffu + ((u >> 16) & 1u);
    return (u16)(u >> 16);
}
__device__ __forceinline__ float bf16f(u16 h) { return __uint_as_float(((u32)h) << 16); }

__device__ __forceinline__ Frag ld_frag8(const u16* p) {
    Frag f;
    uint2 a = *(const uint2*)p;
    uint2 b = *(const uint2*)(p + 4);
    f.i = (intx4){ (int)a.x, (int)a.y, (int)b.x, (int)b.y };
    return f;
}

#define LOG2E 1.44269504088896f

// ---------------- Fused prep: LayerNorm (blocks 0..767) + weight transpose (768..1215) ------
__global__ __launch_bounds__(256) void prep_kernel(
    const float* __restrict__ x,
    const float* __restrict__ g1, const float* __restrict__ b1,
    const float* __restrict__ g2, const float* __restrict__ b2,
    u16* __restrict__ x1h, u16* __restrict__ x1l,
    u16* __restrict__ x2h, u16* __restrict__ x2l,
    const float* __restrict__ Wqkv, u16* __restrict__ wqh, u16* __restrict__ wql,
    const float* __restrict__ Wab,  u16* __restrict__ wah, u16* __restrict__ wal,
    const float* __restrict__ Wo,   const float* __restrict__ Wp,
    u16* __restrict__ wofh, u16* __restrict__ wofl)
{
    __shared__ union { float t[64][65]; float red[4][2]; } u;
    const int tid = threadIdx.x;
    if (blockIdx.x < 768) {
        int row = blockIdx.x;
        const float2 v = ((const float2*)(x + (size_t)row * DIM_))[tid];
        float s  = v.x + v.y;
        float s2 = v.x * v.x + v.y * v.y;
        s  = wave_reduce_sum(s);
        s2 = wave_reduce_sum(s2);
        int w = tid >> 6;
        if ((tid & 63) == 0) { u.red[w][0] = s; u.red[w][1] = s2; }
        __syncthreads();
        float ts  = u.red[0][0] + u.red[1][0] + u.red[2][0] + u.red[3][0];
        float ts2 = u.red[0][1] + u.red[1][1] + u.red[2][1] + u.red[3][1];
        float mean = ts * (1.0f / DIM_);
        float var  = ts2 * (1.0f / DIM_) - mean * mean;
        float rstd = rsqrtf(var + 1e-5f);
        int c0 = tid * 2;
        float n0 = (v.x - mean) * rstd;
        float n1 = (v.y - mean) * rstd;
        float a0 = n0 * g1[c0] + b1[c0], a1 = n1 * g1[c0 + 1] + b1[c0 + 1];
        float c2 = n0 * g2[c0] + b2[c0], c3 = n1 * g2[c0 + 1] + b2[c0 + 1];
        u16 h0 = bf16_rne(a0), h1 = bf16_rne(a1);
        u16 h2 = bf16_rne(c2), h3 = bf16_rne(c3);
        u16 l0 = bf16_rne(a0 - bf16f(h0)), l1 = bf16_rne(a1 - bf16f(h1));
        u16 l2 = bf16_rne(c2 - bf16f(h2)), l3 = bf16_rne(c3 - bf16f(h3));
        size_t o = (size_t)row * 256 + tid;
        ((u32*)x1h)[o] = (u32)h0 | ((u32)h1 << 16);
        ((u32*)x1l)[o] = (u32)l0 | ((u32)l1 << 16);
        ((u32*)x2h)[o] = (u32)h2 | ((u32)h3 << 16);
        ((u32*)x2l)[o] = (u32)l2 | ((u32)l3 << 16);
        return;
    }
    int id = blockIdx.x - 768;
    const float* W; u16 *H, *L; int K, N, Kout, kofs, tile;
    if (id < 192)      { W = Wqkv; H = wqh;  L = wql;  K = 512; N = 1536; Kout = 512; kofs = 0;   tile = id; }
    else if (id < 352) { W = Wab;  H = wah;  L = wal;  K = 512; N = 1280; Kout = 512; kofs = 0;   tile = id - 192; }
    else if (id < 416) { W = Wo;   H = wofh; L = wofl; K = 512; N = 512;  Kout = 768; kofs = 0;   tile = id - 352; }
    else               { W = Wp;   H = wofh; L = wofl; K = 256; N = 512;  Kout = 768; kofs = 512; tile = id - 416; }
    int nx = N >> 6;
    int n0 = (tile % nx) * 64, k0 = (tile / nx) * 64;
    int rr = tid >> 4, c4 = (tid & 15) << 2;
#pragma unroll
    for (int p = 0; p < 4; ++p) {
        int row = rr + p * 16;
        float4 v = *(const float4*)(W + (size_t)(k0 + row) * N + n0 + c4);
        u.t[row][c4 + 0] = v.x; u.t[row][c4 + 1] = v.y;
        u.t[row][c4 + 2] = v.z; u.t[row][c4 + 3] = v.w;
    }
    __syncthreads();
#pragma unroll
    for (int p = 0; p < 4; ++p) {
        int n = rr + p * 16;
        u16 hi[4], lo[4];
#pragma unroll
        for (int c = 0; c < 4; ++c) {
            float v = u.t[c4 + c][n];
            hi[c] = bf16_rne(v);
            lo[c] = bf16_rne(v - bf16f(hi[c]));
        }
        size_t o = (size_t)(n0 + n) * Kout + kofs + k0 + c4;
        *(uint2*)&H[o] = make_uint2((u32)hi[0] | ((u32)hi[1] << 16), (u32)hi[2] | ((u32)hi[3] << 16));
        *(uint2*)&L[o] = make_uint2((u32)lo[0] | ((u32)lo[1] << 16), (u32)lo[2] | ((u32)lo[3] << 16));
    }
}

// ------- Block-diagonal fused input GEMMs: qkv = x1@Wqkv^T ; proj = x2@Wab^T + babcde -------
__global__ __launch_bounds__(256) void gemm_dual(
    const u16* __restrict__ x1h, const u16* __restrict__ x1l,
    const u16* __restrict__ wqh, const u16* __restrict__ wql,
    const u16* __restrict__ x2h, const u16* __restrict__ x2l,
    const u16* __restrict__ wah, const u16* __restrict__ wal,
    const float* __restrict__ babcde,
    float* __restrict__ qkv, float* __restrict__ proj)
{
    __shared__ u16 As[2][64][68];
    __shared__ u16 Bs[2][64][68];
    const int tid = threadIdx.x;
    const int nb = blockIdx.x;
    const u16 *Ah, *Al, *BTh, *BTl; const float* bias; float* C; int N, bn;
    if (nb < 24) { Ah = x1h; Al = x1l; BTh = wqh; BTl = wql; bias = nullptr; C = qkv;  N = 1536; bn = nb * 64; }
    else         { Ah = x2h; Al = x2l; BTh = wah; BTl = wal; bias = babcde; C = proj; N = 1280; bn = (nb - 24) * 64; }
    const int K = 512;
    const int bm = blockIdx.y * 64;
    const int lane = tid & 63, wave = tid >> 6;
    const int m16 = lane & 15, quad = lane >> 4;
    const int wm = (wave >> 1) * 32, wn = (wave & 1) * 32;
    const int r = tid >> 2, c16 = (tid & 3) * 16;

    floatx4 acc[2][2];
#pragma unroll
    for (int i = 0; i < 2; ++i)
#pragma unroll
        for (int j = 0; j < 2; ++j) acc[i][j] = (floatx4){0.f, 0.f, 0.f, 0.f};

    for (int k0 = 0; k0 < K; k0 += 64) {
        __syncthreads();
        {
            const u16* pa = Ah + (size_t)(bm + r) * K + k0 + c16;
            uint4 v0 = *(const uint4*)pa, v1 = *(const uint4*)(pa + 8);
            *(uint2*)&As[0][r][c16 + 0]  = make_uint2(v0.x, v0.y);
            *(uint2*)&As[0][r][c16 + 4]  = make_uint2(v0.z, v0.w);
            *(uint2*)&As[0][r][c16 + 8]  = make_uint2(v1.x, v1.y);
            *(uint2*)&As[0][r][c16 + 12] = make_uint2(v1.z, v1.w);
            const u16* pl = Al + (size_t)(bm + r) * K + k0 + c16;
            uint4 w0 = *(const uint4*)pl, w1 = *(const uint4*)(pl + 8);
            *(uint2*)&As[1][r][c16 + 0]  = make_uint2(w0.x, w0.y);
            *(uint2*)&As[1][r][c16 + 4]  = make_uint2(w0.z, w0.w);
            *(uint2*)&As[1][r][c16 + 8]  = make_uint2(w1.x, w1.y);
            *(uint2*)&As[1][r][c16 + 12] = make_uint2(w1.z, w1.w);
        }
        {
            const u16* pb = BTh + (size_t)(bn + r) * K + k0 + c16;
            uint4 v0 = *(const uint4*)pb, v1 = *(const uint4*)(pb + 8);
            *(uint2*)&Bs[0][r][c16 + 0]  = make_uint2(v0.x, v0.y);
            *(uint2*)&Bs[0][r][c16 + 4]  = make_uint2(v0.z, v0.w);
            *(uint2*)&Bs[0][r][c16 + 8]  = make_uint2(v1.x, v1.y);
            *(uint2*)&Bs[0][r][c16 + 12] = make_uint2(v1.z, v1.w);
            const u16* pc = BTl + (size_t)(bn + r) * K + k0 + c16;
            uint4 w0 = *(const uint4*)pc, w1 = *(const uint4*)(pc + 8);
            *(uint2*)&Bs[1][r][c16 + 0]  = make_uint2(w0.x, w0.y);
            *(uint2*)&Bs[1][r][c16 + 4]  = make_uint2(w0.z, w0.w);
            *(uint2*)&Bs[1][r][c16 + 8]  = make_uint2(w1.x, w1.y);
            *(uint2*)&Bs[1][r][c16 + 12] = make_uint2(w1.z, w1.w);
        }
        __syncthreads();
#pragma unroll
        for (int ks = 0; ks < 2; ++ks) {
            const int ko = ks * 32 + quad * 8;
            Frag a0h = ld_frag8(&As[0][wm + m16][ko]);
            Frag a1h = ld_frag8(&As[0][wm + 16 + m16][ko]);
            Frag a0l = ld_frag8(&As[1][wm + m16][ko]);
            Frag a1l = ld_frag8(&As[1][wm + 16 + m16][ko]);
            Frag b0h = ld_frag8(&Bs[0][wn + m16][ko]);
            Frag b1h = ld_frag8(&Bs[0][wn + 16 + m16][ko]);
            Frag b0l = ld_frag8(&Bs[1][wn + m16][ko]);
            Frag b1l = ld_frag8(&Bs[1][wn + 16 + m16][ko]);
            acc[0][0] = mfma16(a0h, b0h, acc[0][0]);
            acc[0][0] = mfma16(a0l, b0h, acc[0][0]);
            acc[0][0] = mfma16(a0h, b0l, acc[0][0]);
            acc[0][1] = mfma16(a0h, b1h, acc[0][1]);
            acc[0][1] = mfma16(a0l, b1h, acc[0][1]);
            acc[0][1] = mfma16(a0h, b1l, acc[0][1]);
            acc[1][0] = mfma16(a1h, b0h, acc[1][0]);
            acc[1][0] = mfma16(a1l, b0h, acc[1][0]);
            acc[1][0] = mfma16(a1h, b0l, acc[1][0]);
            acc[1][1] = mfma16(a1h, b1h, acc[1][1]);
            acc[1][1] = mfma16(a1l, b1h, acc[1][1]);
            acc[1][1] = mfma16(a1h, b1l, acc[1][1]);
        }
    }
#pragma unroll
    for (int i = 0; i < 2; ++i)
#pragma unroll
        for (int rr = 0; rr < 4; ++rr) {
            int m = bm + wm + i * 16 + quad * 4 + rr;
#pragma unroll
            for (int j = 0; j < 2; ++j) {
                int n = bn + wn + j * 16 + m16;
                float v = acc[i][j][rr];
                if (bias) v += bias[n];
                C[(size_t)m * N + n] = v;
            }
        }
}

// ------- Fused epilogue GEMM: out = [ao | z] @ [Wo;Wp]^T + bo + bp  (M=768,N=512,K=768) -------
// 32x64 tiles -> 192 blocks (was 96); wave computes 16x32 (acc[2]).
__global__ __launch_bounds__(256) void gemm_epilogue(
    const u16* __restrict__ aoh, const u16* __restrict__ aol,
    const u16* __restrict__ zh,  const u16* __restrict__ zl,
    const u16* __restrict__ BTh, const u16* __restrict__ BTl,
    const float* __restrict__ bo, const float* __restrict__ bp,
    float* __restrict__ C)
{
    __shared__ u16 As[2][32][68];
    __shared__ u16 Bs[2][64][68];
    const int tid = threadIdx.x;
    const int bm = blockIdx.y * 32, bn = blockIdx.x * 64;
    const int lane = tid & 63, wave = tid >> 6;
    const int m16 = lane & 15, quad = lane >> 4;
    const int wm = (wave >> 1) * 16, wn = (wave & 1) * 32;
    const int ra = tid >> 3, c8 = (tid & 7) * 8;
    const int rb = tid >> 2, c16 = (tid & 3) * 16;
    const int N = 512, K = 768;

    floatx4 acc[2];
    acc[0] = (floatx4){0.f, 0.f, 0.f, 0.f};
    acc[1] = (floatx4){0.f, 0.f, 0.f, 0.f};

    for (int k0 = 0; k0 < K; k0 += 64) {
        __syncthreads();
        const u16* pah;
        const u16* pal;
        if (k0 < 512) {
            pah = aoh + (size_t)(bm + ra) * 512 + k0 + c8;
            pal = aol + (size_t)(bm + ra) * 512 + k0 + c8;
        } else {
            pah = zh + (size_t)(bm + ra) * 256 + (k0 - 512) + c8;
            pal = zl + (size_t)(bm + ra) * 256 + (k0 - 512) + c8;
        }
        {
            uint4 v = *(const uint4*)pah;
            *(uint2*)&As[0][ra][c8 + 0] = make_uint2(v.x, v.y);
            *(uint2*)&As[0][ra][c8 + 4] = make_uint2(v.z, v.w);
            uint4 w = *(const uint4*)pal;
            *(uint2*)&As[1][ra][c8 + 0] = make_uint2(w.x, w.y);
            *(uint2*)&As[1][ra][c8 + 4] = make_uint2(w.z, w.w);
        }
        {
            const u16* pb = BTh + (size_t)(bn + rb) * K + k0 + c16;
            uint4 v0 = *(const uint4*)pb, v1 = *(const uint4*)(pb + 8);
            *(uint2*)&Bs[0][rb][c16 + 0]  = make_uint2(v0.x, v0.y);
            *(uint2*)&Bs[0][rb][c16 + 4]  = make_uint2(v0.z, v0.w);
            *(uint2*)&Bs[0][rb][c16 + 8]  = make_uint2(v1.x, v1.y);
            *(uint2*)&Bs[0][rb][c16 + 12] = make_uint2(v1.z, v1.w);
            const u16* pc = BTl + (size_t)(bn + rb) * K + k0 + c16;
            uint4 w0 = *(const uint4*)pc, w1 = *(const uint4*)(pc + 8);
            *(uint2*)&Bs[1][rb][c16 + 0]  = make_uint2(w0.x, w0.y);
            *(uint2*)&Bs[1][rb][c16 + 4]  = make_uint2(w0.z, w0.w);
            *(uint2*)&Bs[1][rb][c16 + 8]  = make_uint2(w1.x, w1.y);
            *(uint2*)&Bs[1][rb][c16 + 12] = make_uint2(w1.z, w1.w);
        }
        __syncthreads();
#pragma unroll
        for (int ks = 0; ks < 2; ++ks) {
            const int ko = ks * 32 + quad * 8;
            Frag ah = ld_frag8(&As[0][wm + m16][ko]);
            Frag al = ld_frag8(&As[1][wm + m16][ko]);
            Frag b0h = ld_frag8(&Bs[0][wn + m16][ko]);
            Frag b1h = ld_frag8(&Bs[0][wn + 16 + m16][ko]);
            Frag b0l = ld_frag8(&Bs[1][wn + m16][ko]);
            Frag b1l = ld_frag8(&Bs[1][wn + 16 + m16][ko]);
            acc[0] = mfma16(ah, b0h, acc[0]);
            acc[0] = mfma16(al, b0h, acc[0]);
            acc[0] = mfma16(ah, b0l, acc[0]);
            acc[1] = mfma16(ah, b1h, acc[1]);
            acc[1] = mfma16(al, b1h, acc[1]);
            acc[1] = mfma16(ah, b1l, acc[1]);
        }
    }
#pragma unroll
    for (int rr = 0; rr < 4; ++rr) {
        int m = bm + wm + quad * 4 + rr;
#pragma unroll
        for (int j = 0; j < 2; ++j) {
            int n = bn + wn + j * 16 + m16;
            C[(size_t)m * N + n] = acc[j][rr] + bo[n] + bp[n];
        }
    }
}

// ---------------- Flash-style MFMA attention ----------------
__global__ __launch_bounds__(256) void attn_mfma(
    const float* __restrict__ qkv, u16* __restrict__ aoh, u16* __restrict__ aol)
{
    __shared__ union { u16 Ks[192][68]; u16 P[64][196]; } KP;
    __shared__ u16 Vt[64][196];
    const int qt = blockIdx.x, h = blockIdx.y, b = blockIdx.z;
    const int tid = threadIdx.x;
    const int lane = tid & 63, wave = tid >> 6;
    const int m16 = lane & 15, quad = lane >> 4;
    const size_t base = (size_t)(b * T_) * 1536 + h * 64;

    for (int i = tid; i < 192 * 16; i += 256) {
        int row = i >> 4, c4 = (i & 15) << 2;
        float4 kv = *(const float4*)(qkv + base + (size_t)row * 1536 + 512 + c4);
        *(uint2*)&KP.Ks[row][c4] = make_uint2(pack_rne(kv.x, kv.y), pack_rne(kv.z, kv.w));
        float4 vv = *(const float4*)(qkv + base + (size_t)row * 1536 + 1024 + c4);
        Vt[c4 + 0][row] = bf16_rne(vv.x);
        Vt[c4 + 1][row] = bf16_rne(vv.y);
        Vt[c4 + 2][row] = bf16_rne(vv.z);
        Vt[c4 + 3][row] = bf16_rne(vv.w);
    }

    Frag qf0, qf1;
    {
        const float s = 0.125f * LOG2E;   // fold log2e: exp(x) = exp2(x*log2e)
        const float* qp = qkv + base + (size_t)(qt * 64 + wave * 16 + m16) * 1536 + quad * 8;
        float4 u0 = *(const float4*)qp;
        float4 u1 = *(const float4*)(qp + 4);
        float4 u2 = *(const float4*)(qp + 32);
        float4 u3 = *(const float4*)(qp + 36);
        qf0.i = (intx4){ (int)pack_rne(u0.x * s, u0.y * s), (int)pack_rne(u0.z * s, u0.w * s),
                         (int)pack_rne(u1.x * s, u1.y * s), (int)pack_rne(u1.z * s, u1.w * s) };
        qf1.i = (intx4){ (int)pack_rne(u2.x * s, u2.y * s), (int)pack_rne(u2.z * s, u2.w * s),
                         (int)pack_rne(u3.x * s, u3.y * s), (int)pack_rne(u3.z * s, u3.w * s) };
    }
    __syncthreads();

    float ev[12][4];
    float rsum[4] = {0.f, 0.f, 0.f, 0.f};
#pragma unroll
    for (int tt = 0; tt < 12; ++tt) {
        Frag kb0 = ld_frag8(&KP.Ks[tt * 16 + m16][quad * 8]);
        Frag kb1 = ld_frag8(&KP.Ks[tt * 16 + m16][32 + quad * 8]);
        floatx4 accs = (floatx4){0.f, 0.f, 0.f, 0.f};
        accs = mfma16(qf0, kb0, accs);
        accs = mfma16(qf1, kb1, accs);
#pragma unroll
        for (int rr = 0; rr < 4; ++rr) {
            float e = exp2f(accs[rr]);
            ev[tt][rr] = e;
            rsum[rr] += e;
        }
    }
#pragma unroll
    for (int rr = 0; rr < 4; ++rr) {
        float v = rsum[rr];
        v += __shfl_xor(v, 1, 64);
        v += __shfl_xor(v, 2, 64);
        v += __shfl_xor(v, 4, 64);
        v += __shfl_xor(v, 8, 64);
        rsum[rr] = 1.0f / v;
    }

    __syncthreads();
#pragma unroll
    for (int tt = 0; tt < 12; ++tt)
#pragma unroll
        for (int rr = 0; rr < 4; ++rr)
            KP.P[wave * 16 + quad * 4 + rr][tt * 16 + m16] = bf16_rne(ev[tt][rr]);

    floatx4 acco[4];
#pragma unroll
    for (int dt = 0; dt < 4; ++dt) acco[dt] = (floatx4){0.f, 0.f, 0.f, 0.f};
#pragma unroll
    for (int ts = 0; ts < 6; ++ts) {
        Frag pf = ld_frag8(&KP.P[wave * 16 + m16][ts * 32 + quad * 8]);
#pragma unroll
        for (int dt = 0; dt < 4; ++dt) {
            Frag vf = ld_frag8(&Vt[dt * 16 + m16][ts * 32 + quad * 8]);
            acco[dt] = mfma16(pf, vf, acco[dt]);
        }
    }
#pragma unroll
    for (int dt = 0; dt < 4; ++dt)
#pragma unroll
        for (int rr = 0; rr < 4; ++rr) {
            float o = acco[dt][rr] * rsum[rr];
            size_t idx = (size_t)(b * T_ + qt * 64 + wave * 16 + quad * 4 + rr) * 512
                       + h * 64 + dt * 16 + m16;
            u16 hi = bf16_rne(o);
            aoh[idx] = hi;
            aol[idx] = bf16_rne(o - bf16f(hi));
        }
}

// ---------------- Trittention cubic scores via MFMA -> rs, rt (partials) ----------------
// Round-4 optimum structure; log2e folded into a-quantization (exp2f = single v_exp_f32).
__global__ __launch_bounds__(256, 3) void tritt_score_mfma(
    const float* __restrict__ proj, float* __restrict__ rs_g, float* __restrict__ rt_g)
{
    __shared__ u32 a_lds[96 * 36];
    __shared__ u32 b_lds[48 * 36];
    __shared__ float rs_lds[96][32];
    __shared__ float rt_lds[48][32];

    const int h = blockIdx.y, b = blockIdx.z;
    const int qt = blockIdx.x >> 3;          // 0..5
    const int sc = (blockIdx.x >> 2) & 1;    // 0..1
    const int tc = blockIdx.x & 3;           // 0..3
    const int q0 = qt * 32, s0 = sc * 96, t0 = tc * 48;
    const int tid  = threadIdx.x;
    const int lane = tid & 63, wave = tid >> 6;
    const int m16  = lane & 15, quad = lane >> 4;
    const int bh = b * CH + h;
    const size_t rowbase = (size_t)(b * T_) * 1280 + h * 64;
    const float kA = 0.015625f * LOG2E;   // 1/64 * log2e: scores exit MFMA pre-scaled for exp2

    for (int i = tid; i < 96 * 32; i += 256) {
        int row = i >> 5, cp = i & 31;
        const float2 va = *(const float2*)(proj + rowbase + (size_t)(s0 + row) * 1280 + 0 + cp * 2);
        a_lds[row * 36 + cp] = pack_rne(va.x * kA, va.y * kA);
        if (i < 48 * 32) {
            const float2 vb = *(const float2*)(proj + rowbase + (size_t)(t0 + row) * 1280 + 256 + cp * 2);
            b_lds[row * 36 + cp] = pack_rne(vb.x, vb.y);
        }
    }

    Frag cf[2][2];
#pragma unroll
    for (int jq = 0; jq < 2; ++jq) {
        const float* cp = proj + rowbase + (size_t)(q0 + jq * 16 + m16) * 1280 + 512 + quad * 8;
        float4 u0 = *(const float4*)(cp);
        float4 u1 = *(const float4*)(cp + 4);
        float4 u2 = *(const float4*)(cp + 32);
        float4 u3 = *(const float4*)(cp + 36);
        cf[jq][0].i = (intx4){ (int)pack_rne(u0.x, u0.y), (int)pack_rne(u0.z, u0.w),
                               (int)pack_rne(u1.x, u1.y), (int)pack_rne(u1.z, u1.w) };
        cf[jq][1].i = (intx4){ (int)pack_rne(u2.x, u2.y), (int)pack_rne(u2.z, u2.w),
                               (int)pack_rne(u3.x, u3.y), (int)pack_rne(u3.z, u3.w) };
    }
    __syncthreads();

    float rt_acc[3][4][2] = {};

    for (int si = 0; si < 24; ++si) {
        const int srow = wave * 24 + si;
        f32x2 af2[8];
        {
            intx4 av0 = *(const intx4*)(a_lds + srow * 36 + quad * 4);
            intx4 av1 = *(const intx4*)(a_lds + srow * 36 + 16 + quad * 4);
#pragma unroll
            for (int j = 0; j < 4; ++j) {
                u32 d0 = (u32)av0[j];
                af2[j] = (f32x2){ __uint_as_float(d0 << 16), __uint_as_float(d0 & 0xffff0000u) };
                u32 d1 = (u32)av1[j];
                af2[4 + j] = (f32x2){ __uint_as_float(d1 << 16), __uint_as_float(d1 & 0xffff0000u) };
            }
        }
        float rs_s[2] = {0.f, 0.f};
#pragma unroll
        for (int tt = 0; tt < 3; ++tt) {
            const u32* bp = b_lds + (tt * 16 + m16) * 36;
            intx4 bv0 = *(const intx4*)(bp + quad * 4);
            intx4 bv1 = *(const intx4*)(bp + 16 + quad * 4);
            Frag w0, w1;
#pragma unroll
            for (int j = 0; j < 4; ++j) {
                u32 d0 = (u32)bv0[j];
                f32x2 p0 = af2[j] * (f32x2){ __uint_as_float(d0 << 16),
                                             __uint_as_float(d0 & 0xffff0000u) };
                w0.i[j] = (int)__builtin_amdgcn_perm(__float_as_uint(p0.y),
                                                     __float_as_uint(p0.x), 0x07060302u);
                u32 d1 = (u32)bv1[j];
                f32x2 p1 = af2[4 + j] * (f32x2){ __uint_as_float(d1 << 16),
                                                 __uint_as_float(d1 & 0xffff0000u) };
                w1.i[j] = (int)__builtin_amdgcn_perm(__float_as_uint(p1.y),
                                                     __float_as_uint(p1.x), 0x07060302u);
            }
#pragma unroll
            for (int jq = 0; jq < 2; ++jq) {
                floatx4 acc = (floatx4){0.f, 0.f, 0.f, 0.f};
                acc = mfma16(w0, cf[jq][0], acc);
                acc = mfma16(w1, cf[jq][1], acc);
                // lane holds E[t_local = tt*16 + quad*4 + rr][q = q0 + jq*16 + m16]
#pragma unroll
                for (int rr = 0; rr < 4; ++rr) {
                    float e = exp2f(acc[rr]);
                    rt_acc[tt][rr][jq] += e;
                    rs_s[jq] += e;
                }
            }
        }
#pragma unroll
        for (int jq = 0; jq < 2; ++jq) {
            float v = rs_s[jq];
            v += __shfl_xor(v, 16, 64);
            v += __shfl_xor(v, 32, 64);
            if (lane < 16) rs_lds[srow][jq * 16 + m16] = v;
        }
    }

    __syncthreads();
    for (int w = 0; w < 4; ++w) {
        if (wave == w) {
#pragma unroll
            for (int tt = 0; tt < 3; ++tt)
#pragma unroll
                for (int rr = 0; rr < 4; ++rr) {
                    int t = tt * 16 + quad * 4 + rr;
#pragma unroll
                    for (int jq = 0; jq < 2; ++jq) {
                        if (w == 0) rt_lds[t][jq * 16 + m16] = rt_acc[tt][rr][jq];
                        else        rt_lds[t][jq * 16 + m16] += rt_acc[tt][rr][jq];
                    }
                }
        }
        __syncthreads();
    }
    for (int i = tid; i < 32 * 96; i += 256) {
        int qq = i / 96, ss = i % 96;
        rs_g[((size_t)(tc * 16 + bh) * T_ + q0 + qq) * T_ + s0 + ss] = rs_lds[ss][qq];
    }
    for (int i = tid; i < 32 * 48; i += 256) {
        int qq = i / 48, t2 = i % 48;
        rt_g[((size_t)(sc * 16 + bh) * T_ + q0 + qq) * T_ + t0 + t2] = rt_lds[t2][qq];
    }
}

// ------- zgemm: z[q][d] = ( [rs|rt] @ DE^T ) / Z  per bh; d split across 2 blocks -------
// Block = (mt 0..2, dhalf 0..1) x bh: 96 blocks (was 48). 64q x 32d; wave = 32x16 (acc[2]).
__global__ __launch_bounds__(256) void zgemm(
    const float* __restrict__ rs_g, const float* __restrict__ rt_g,
    const float* __restrict__ proj, u16* __restrict__ zzh, u16* __restrict__ zzl)
{
    __shared__ u16 As[2][64][68];
    __shared__ u16 Bs[32][68];
    __shared__ float zred[64][4];
    __shared__ float Zl[64];
    const int mt = blockIdx.x >> 1, dh2 = blockIdx.x & 1, bh = blockIdx.y;
    const int b = bh >> 2, h = bh & 3;
    const int q0 = mt * 64;
    const int tid = threadIdx.x;
    const int lane = tid & 63, wave = tid >> 6;
    const int m16 = lane & 15, quad = lane >> 4;
    const int wm = (wave >> 1) * 32, wn = (wave & 1) * 16;
    const int r = tid >> 2, c16 = (tid & 3) * 16;

    {
        float zp = 0.f;
        const int j = tid & 3;
#pragma unroll
        for (int tc = 0; tc < 4; ++tc) {
            const float* p = rs_g + ((size_t)(tc * 16 + bh) * T_ + q0 + r) * T_ + j * 48;
#pragma unroll
            for (int s = 0; s < 48; s += 4) {
                float4 v = *(const float4*)(p + s);
                zp += (v.x + v.y) + (v.z + v.w);
            }
        }
        zred[r][j] = zp;
    }
    __syncthreads();
    if (tid < 64)
        Zl[tid] = 1.0f / (zred[tid][0] + zred[tid][1] + zred[tid][2] + zred[tid][3]);

    floatx4 acc[2];
    acc[0] = (floatx4){0.f, 0.f, 0.f, 0.f};
    acc[1] = (floatx4){0.f, 0.f, 0.f, 0.f};

    for (int k0 = 0; k0 < 384; k0 += 64) {
        __syncthreads();
        {   // G staging: sum partials, pack hi/lo
            float g[16];
#pragma unroll
            for (int i = 0; i < 16; ++i) g[i] = 0.f;
            if (k0 < 192) {
#pragma unroll
                for (int tc = 0; tc < 4; ++tc) {
                    const float* p = rs_g + ((size_t)(tc * 16 + bh) * T_ + q0 + r) * T_ + k0 + c16;
#pragma unroll
                    for (int i = 0; i < 16; i += 4) {
                        float4 v = *(const float4*)(p + i);
                        g[i] += v.x; g[i + 1] += v.y; g[i + 2] += v.z; g[i + 3] += v.w;
                    }
                }
            } else {
#pragma unroll
                for (int sc = 0; sc < 2; ++sc) {
                    const float* p = rt_g + ((size_t)(sc * 16 + bh) * T_ + q0 + r) * T_ + (k0 - 192) + c16;
#pragma unroll
                    for (int i = 0; i < 16; i += 4) {
                        float4 v = *(const float4*)(p + i);
                        g[i] += v.x; g[i + 1] += v.y; g[i + 2] += v.z; g[i + 3] += v.w;
                    }
                }
            }
#pragma unroll
            for (int i = 0; i < 16; ++i) {
                u16 hi = bf16_rne(g[i]);
                As[0][r][c16 + i] = hi;
                As[1][r][c16 + i] = bf16_rne(g[i] - bf16f(hi));
            }
        }
        {   // DE^T staging from proj: Bs[d_local][s_local], 32 d-cols for this d-half
            const int colbase = (k0 < 192 ? 768 : 1024) + h * 64 + dh2 * 32;
            const int s0 = (k0 < 192 ? k0 : k0 - 192);
            const int sl = tid >> 2;          // 0..63
            const int d4b = (tid & 3) * 4;    // 0..12
#pragma unroll
            for (int i = 0; i < 2; ++i) {
                int dd = d4b + i * 16;        // 0..28
                float4 v = *(const float4*)(proj + (size_t)(b * T_ + s0 + sl) * 1280 + colbase + dd);
                Bs[dd + 0][sl] = bf16_rne(v.x);
                Bs[dd + 1][sl] = bf16_rne(v.y);
                Bs[dd + 2][sl] = bf16_rne(v.z);
                Bs[dd + 3][sl] = bf16_rne(v.w);
            }
        }
        __syncthreads();
#pragma unroll
        for (int ks = 0; ks < 2; ++ks) {
            const int ko = ks * 32 + quad * 8;
            Frag g0h = ld_frag8(&As[0][wm + m16][ko]);
            Frag g1h = ld_frag8(&As[0][wm + 16 + m16][ko]);
            Frag g0l = ld_frag8(&As[1][wm + m16][ko]);
            Frag g1l = ld_frag8(&As[1][wm + 16 + m16][ko]);
            Frag d0 = ld_frag8(&Bs[wn + m16][ko]);
            acc[0] = mfma16(g0h, d0, acc[0]);
            acc[0] = mfma16(g0l, d0, acc[0]);
            acc[1] = mfma16(g1h, d0, acc[1]);
            acc[1] = mfma16(g1l, d0, acc[1]);
        }
    }
#pragma unroll
    for (int i = 0; i < 2; ++i)
#pragma unroll
        for (int rr = 0; rr < 4; ++rr) {
            int m = wm + i * 16 + quad * 4 + rr;
            int d = dh2 * 32 + wn + m16;
            float zv = acc[i][rr] * Zl[m];
            size_t idx = (size_t)(b * T_ + q0 + m) * 256 + h * 64 + d;
            u16 hi = bf16_rne(zv);
            zzh[idx] = hi;
            zzl[idx] = bf16_rne(zv - bf16f(hi));
        }
}

extern "C" void kernel_launch(void* const* d_in, const int* in_sizes, int n_in,
                              void* d_out, int out_size, void* d_ws, size_t ws_size,
                              hipStream_t stream)
{
    const float* x      = (const float*)d_in[0];
    const float* ln1_g  = (const float*)d_in[1];
    const float* ln1_b  = (const float*)d_in[2];
    const float* Wqkv   = (const float*)d_in[3];
    const float* Wo     = (const float*)d_in[4];
    const float* bo     = (const float*)d_in[5];
    const float* ln2_g  = (const float*)d_in[6];
    const float* ln2_b  = (const float*)d_in[7];
    const float* Wabcde = (const float*)d_in[8];
    const float* babcde = (const float*)d_in[9];
    const float* Wp     = (const float*)d_in[10];
    const float* bp     = (const float*)d_in[11];
    float* out = (float*)d_out;

    // ---- workspace layout (f32 units), total 6,684,672 f = 25.5 MiB ----
    float* ws   = (float*)d_ws;
    float* proj = ws;                              // 983,040 f (alive through zgemm)
    u16* wofh   = (u16*)(proj + 983040);           // 512*768 hi/lo = 393,216 f
    u16* wofl   = wofh + 393216;
    u16* aoh    = (u16*)(ws + 1376256);            // 768*512 hi/lo = 393,216 f
    u16* aol    = aoh + 393216;
    u16* zh     = (u16*)(ws + 1769472);            // z hi/lo = 196,608 f
    u16* zl     = zh + 196608;
    float* rs   = ws + 1966080;                    // 4 tc-partials: 2,359,296 f
    float* rt   = rs + 2359296;                    // 2 sc-partials used (region 2,359,296 f)
    // aliases (disjoint lifetimes):
    float* qkv = rs;                               // dead before rs written
    u16* x1h = (u16*)(rs + 1179648);               // x bufs in rs tail
    u16* x1l = x1h + 393216;
    u16* x2h = x1l + 393216;
    u16* x2l = x2h + 393216;
    u16* wqh = (u16*)rt;                           // Wqkv^T in rt head (dead before rt written)
    u16* wql = wqh + 786432;
    u16* wah = (u16*)(rt + 786432);                // Wabcde^T in rt tail (dead before tritt)
    u16* wal = wah + 655360;

    prep_kernel<<<1216, 256, 0, stream>>>(x, ln1_g, ln1_b, ln2_g, ln2_b,
                                          x1h, x1l, x2h, x2l,
                                          Wqkv, wqh, wql, Wabcde, wah, wal,
                                          Wo, Wp, wofh, wofl);
    gemm_dual<<<dim3(44, 12), 256, 0, stream>>>(x1h, x1l, wqh, wql, x2h, x2l, wah, wal,
                                                babcde, qkv, proj);
    attn_mfma<<<dim3(3, AH, B_), 256, 0, stream>>>(qkv, aoh, aol);
    tritt_score_mfma<<<dim3(48, CH, B_), 256, 0, stream>>>(proj, rs, rt);
    zgemm<<<dim3(6, 16), 256, 0, stream>>>(rs, rt, proj, zh, zl);
    gemm_epilogue<<<dim3(8, 24), 256, 0, stream>>>(aoh, aol, zh, zl, wofh, wofl, bo, bp, out);
}

// Round 12
// 183.635 us; speedup vs baseline: 1.0687x; 1.0687x over previous
//
#include <hip/hip_runtime.h>
#include <cstdint>

// MixedAttention: attention (8 heads) + trittention (4 heads, cubic scores), T=192, DIM=512.
// Round 11: exp2f() -> __builtin_amdgcn_exp2f (raw v_exp_f32). r10's exp2f regressed tritt
// 53.8->65.6us because ocml exp2 carries a denormal guard (~6 VALU vs 2 for __expf). With
// log2e folded into staging, the raw builtin is 1 op/element. zgemm d-split + epilogue
// M-split kept (netted ~-5us in r10). tritt structure untouched (r4 optimum).

#define B_   4
#define T_   192
#define DIM_ 512
#define AH   8
#define CH   4

typedef unsigned short u16;
typedef unsigned int   u32;
typedef __attribute__((ext_vector_type(8))) short short8;
typedef __attribute__((ext_vector_type(4))) float floatx4;
typedef __attribute__((ext_vector_type(4))) int intx4;
typedef __attribute__((ext_vector_type(2))) float f32x2;

union Frag { intx4 i; short8 s; };

__device__ __forceinline__ floatx4 mfma16(Frag a, Frag b, floatx4 c) {
    return __builtin_amdgcn_mfma_f32_16x16x32_bf16(a.s, b.s, c, 0, 0, 0);
}

__device__ __forceinline__ float fexp2(float x) {
    return __builtin_amdgcn_exp2f(x);   // bare v_exp_f32, no ocml denormal guard
}

__device__ __forceinline__ float wave_reduce_sum(float v) {
#pragma unroll
    for (int off = 32; off >= 1; off >>= 1)
        v += __shfl_xor(v, off, 64);
    return v;
}

__device__ __forceinline__ u32 pack_rne(float x, float y) {
    u32 ux = __float_as_uint(x);
    u32 uy = __float_as_uint(y);
    ux += 0x7fffu + ((ux >> 16) & 1u);
    uy += 0x7fffu + ((uy >> 16) & 1u);
    return (ux >> 16) | (uy & 0xffff0000u);
}
__device__ __forceinline__ u16 bf16_rne(float x) {
    u32 u = __float_as_uint(x);
    u += 0x7fffu + ((u >> 16) & 1u);
    return (u16)(u >> 16);
}
__device__ __forceinline__ float bf16f(u16 h) { return __uint_as_float(((u32)h) << 16); }

__device__ __forceinline__ Frag ld_frag8(const u16* p) {
    Frag f;
    uint2 a = *(const uint2*)p;
    uint2 b = *(const uint2*)(p + 4);
    f.i = (intx4){ (int)a.x, (int)a.y, (int)b.x, (int)b.y };
    return f;
}

#define LOG2E 1.44269504088896f

// ---------------- Fused prep: LayerNorm (blocks 0..767) + weight transpose (768..1215) ------
__global__ __launch_bounds__(256) void prep_kernel(
    const float* __restrict__ x,
    const float* __restrict__ g1, const float* __restrict__ b1,
    const float* __restrict__ g2, const float* __restrict__ b2,
    u16* __restrict__ x1h, u16* __restrict__ x1l,
    u16* __restrict__ x2h, u16* __restrict__ x2l,
    const float* __restrict__ Wqkv, u16* __restrict__ wqh, u16* __restrict__ wql,
    const float* __restrict__ Wab,  u16* __restrict__ wah, u16* __restrict__ wal,
    const float* __restrict__ Wo,   const float* __restrict__ Wp,
    u16* __restrict__ wofh, u16* __restrict__ wofl)
{
    __shared__ union { float t[64][65]; float red[4][2]; } u;
    const int tid = threadIdx.x;
    if (blockIdx.x < 768) {
        int row = blockIdx.x;
        const float2 v = ((const float2*)(x + (size_t)row * DIM_))[tid];
        float s  = v.x + v.y;
        float s2 = v.x * v.x + v.y * v.y;
        s  = wave_reduce_sum(s);
        s2 = wave_reduce_sum(s2);
        int w = tid >> 6;
        if ((tid & 63) == 0) { u.red[w][0] = s; u.red[w][1] = s2; }
        __syncthreads();
        float ts  = u.red[0][0] + u.red[1][0] + u.red[2][0] + u.red[3][0];
        float ts2 = u.red[0][1] + u.red[1][1] + u.red[2][1] + u.red[3][1];
        float mean = ts * (1.0f / DIM_);
        float var  = ts2 * (1.0f / DIM_) - mean * mean;
        float rstd = rsqrtf(var + 1e-5f);
        int c0 = tid * 2;
        float n0 = (v.x - mean) * rstd;
        float n1 = (v.y - mean) * rstd;
        float a0 = n0 * g1[c0] + b1[c0], a1 = n1 * g1[c0 + 1] + b1[c0 + 1];
        float c2 = n0 * g2[c0] + b2[c0], c3 = n1 * g2[c0 + 1] + b2[c0 + 1];
        u16 h0 = bf16_rne(a0), h1 = bf16_rne(a1);
        u16 h2 = bf16_rne(c2), h3 = bf16_rne(c3);
        u16 l0 = bf16_rne(a0 - bf16f(h0)), l1 = bf16_rne(a1 - bf16f(h1));
        u16 l2 = bf16_rne(c2 - bf16f(h2)), l3 = bf16_rne(c3 - bf16f(h3));
        size_t o = (size_t)row * 256 + tid;
        ((u32*)x1h)[o] = (u32)h0 | ((u32)h1 << 16);
        ((u32*)x1l)[o] = (u32)l0 | ((u32)l1 << 16);
        ((u32*)x2h)[o] = (u32)h2 | ((u32)h3 << 16);
        ((u32*)x2l)[o] = (u32)l2 | ((u32)l3 << 16);
        return;
    }
    int id = blockIdx.x - 768;
    const float* W; u16 *H, *L; int K, N, Kout, kofs, tile;
    if (id < 192)      { W = Wqkv; H = wqh;  L = wql;  K = 512; N = 1536; Kout = 512; kofs = 0;   tile = id; }
    else if (id < 352) { W = Wab;  H = wah;  L = wal;  K = 512; N = 1280; Kout = 512; kofs = 0;   tile = id - 192; }
    else if (id < 416) { W = Wo;   H = wofh; L = wofl; K = 512; N = 512;  Kout = 768; kofs = 0;   tile = id - 352; }
    else               { W = Wp;   H = wofh; L = wofl; K = 256; N = 512;  Kout = 768; kofs = 512; tile = id - 416; }
    int nx = N >> 6;
    int n0 = (tile % nx) * 64, k0 = (tile / nx) * 64;
    int rr = tid >> 4, c4 = (tid & 15) << 2;
#pragma unroll
    for (int p = 0; p < 4; ++p) {
        int row = rr + p * 16;
        float4 v = *(const float4*)(W + (size_t)(k0 + row) * N + n0 + c4);
        u.t[row][c4 + 0] = v.x; u.t[row][c4 + 1] = v.y;
        u.t[row][c4 + 2] = v.z; u.t[row][c4 + 3] = v.w;
    }
    __syncthreads();
#pragma unroll
    for (int p = 0; p < 4; ++p) {
        int n = rr + p * 16;
        u16 hi[4], lo[4];
#pragma unroll
        for (int c = 0; c < 4; ++c) {
            float v = u.t[c4 + c][n];
            hi[c] = bf16_rne(v);
            lo[c] = bf16_rne(v - bf16f(hi[c]));
        }
        size_t o = (size_t)(n0 + n) * Kout + kofs + k0 + c4;
        *(uint2*)&H[o] = make_uint2((u32)hi[0] | ((u32)hi[1] << 16), (u32)hi[2] | ((u32)hi[3] << 16));
        *(uint2*)&L[o] = make_uint2((u32)lo[0] | ((u32)lo[1] << 16), (u32)lo[2] | ((u32)lo[3] << 16));
    }
}

// ------- Block-diagonal fused input GEMMs: qkv = x1@Wqkv^T ; proj = x2@Wab^T + babcde -------
__global__ __launch_bounds__(256) void gemm_dual(
    const u16* __restrict__ x1h, const u16* __restrict__ x1l,
    const u16* __restrict__ wqh, const u16* __restrict__ wql,
    const u16* __restrict__ x2h, const u16* __restrict__ x2l,
    const u16* __restrict__ wah, const u16* __restrict__ wal,
    const float* __restrict__ babcde,
    float* __restrict__ qkv, float* __restrict__ proj)
{
    __shared__ u16 As[2][64][68];
    __shared__ u16 Bs[2][64][68];
    const int tid = threadIdx.x;
    const int nb = blockIdx.x;
    const u16 *Ah, *Al, *BTh, *BTl; const float* bias; float* C; int N, bn;
    if (nb < 24) { Ah = x1h; Al = x1l; BTh = wqh; BTl = wql; bias = nullptr; C = qkv;  N = 1536; bn = nb * 64; }
    else         { Ah = x2h; Al = x2l; BTh = wah; BTl = wal; bias = babcde; C = proj; N = 1280; bn = (nb - 24) * 64; }
    const int K = 512;
    const int bm = blockIdx.y * 64;
    const int lane = tid & 63, wave = tid >> 6;
    const int m16 = lane & 15, quad = lane >> 4;
    const int wm = (wave >> 1) * 32, wn = (wave & 1) * 32;
    const int r = tid >> 2, c16 = (tid & 3) * 16;

    floatx4 acc[2][2];
#pragma unroll
    for (int i = 0; i < 2; ++i)
#pragma unroll
        for (int j = 0; j < 2; ++j) acc[i][j] = (floatx4){0.f, 0.f, 0.f, 0.f};

    for (int k0 = 0; k0 < K; k0 += 64) {
        __syncthreads();
        {
            const u16* pa = Ah + (size_t)(bm + r) * K + k0 + c16;
            uint4 v0 = *(const uint4*)pa, v1 = *(const uint4*)(pa + 8);
            *(uint2*)&As[0][r][c16 + 0]  = make_uint2(v0.x, v0.y);
            *(uint2*)&As[0][r][c16 + 4]  = make_uint2(v0.z, v0.w);
            *(uint2*)&As[0][r][c16 + 8]  = make_uint2(v1.x, v1.y);
            *(uint2*)&As[0][r][c16 + 12] = make_uint2(v1.z, v1.w);
            const u16* pl = Al + (size_t)(bm + r) * K + k0 + c16;
            uint4 w0 = *(const uint4*)pl, w1 = *(const uint4*)(pl + 8);
            *(uint2*)&As[1][r][c16 + 0]  = make_uint2(w0.x, w0.y);
            *(uint2*)&As[1][r][c16 + 4]  = make_uint2(w0.z, w0.w);
            *(uint2*)&As[1][r][c16 + 8]  = make_uint2(w1.x, w1.y);
            *(uint2*)&As[1][r][c16 + 12] = make_uint2(w1.z, w1.w);
        }
        {
            const u16* pb = BTh + (size_t)(bn + r) * K + k0 + c16;
            uint4 v0 = *(const uint4*)pb, v1 = *(const uint4*)(pb + 8);
            *(uint2*)&Bs[0][r][c16 + 0]  = make_uint2(v0.x, v0.y);
            *(uint2*)&Bs[0][r][c16 + 4]  = make_uint2(v0.z, v0.w);
            *(uint2*)&Bs[0][r][c16 + 8]  = make_uint2(v1.x, v1.y);
            *(uint2*)&Bs[0][r][c16 + 12] = make_uint2(v1.z, v1.w);
            const u16* pc = BTl + (size_t)(bn + r) * K + k0 + c16;
            uint4 w0 = *(const uint4*)pc, w1 = *(const uint4*)(pc + 8);
            *(uint2*)&Bs[1][r][c16 + 0]  = make_uint2(w0.x, w0.y);
            *(uint2*)&Bs[1][r][c16 + 4]  = make_uint2(w0.z, w0.w);
            *(uint2*)&Bs[1][r][c16 + 8]  = make_uint2(w1.x, w1.y);
            *(uint2*)&Bs[1][r][c16 + 12] = make_uint2(w1.z, w1.w);
        }
        __syncthreads();
#pragma unroll
        for (int ks = 0; ks < 2; ++ks) {
            const int ko = ks * 32 + quad * 8;
            Frag a0h = ld_frag8(&As[0][wm + m16][ko]);
            Frag a1h = ld_frag8(&As[0][wm + 16 + m16][ko]);
            Frag a0l = ld_frag8(&As[1][wm + m16][ko]);
            Frag a1l = ld_frag8(&As[1][wm + 16 + m16][ko]);
            Frag b0h = ld_frag8(&Bs[0][wn + m16][ko]);
            Frag b1h = ld_frag8(&Bs[0][wn + 16 + m16][ko]);
            Frag b0l = ld_frag8(&Bs[1][wn + m16][ko]);
            Frag b1l = ld_frag8(&Bs[1][wn + 16 + m16][ko]);
            acc[0][0] = mfma16(a0h, b0h, acc[0][0]);
            acc[0][0] = mfma16(a0l, b0h, acc[0][0]);
            acc[0][0] = mfma16(a0h, b0l, acc[0][0]);
            acc[0][1] = mfma16(a0h, b1h, acc[0][1]);
            acc[0][1] = mfma16(a0l, b1h, acc[0][1]);
            acc[0][1] = mfma16(a0h, b1l, acc[0][1]);
            acc[1][0] = mfma16(a1h, b0h, acc[1][0]);
            acc[1][0] = mfma16(a1l, b0h, acc[1][0]);
            acc[1][0] = mfma16(a1h, b0l, acc[1][0]);
            acc[1][1] = mfma16(a1h, b1h, acc[1][1]);
            acc[1][1] = mfma16(a1l, b1h, acc[1][1]);
            acc[1][1] = mfma16(a1h, b1l, acc[1][1]);
        }
    }
#pragma unroll
    for (int i = 0; i < 2; ++i)
#pragma unroll
        for (int rr = 0; rr < 4; ++rr) {
            int m = bm + wm + i * 16 + quad * 4 + rr;
#pragma unroll
            for (int j = 0; j < 2; ++j) {
                int n = bn + wn + j * 16 + m16;
                float v = acc[i][j][rr];
                if (bias) v += bias[n];
                C[(size_t)m * N + n] = v;
            }
        }
}

// ------- Fused epilogue GEMM: out = [ao | z] @ [Wo;Wp]^T + bo + bp  (M=768,N=512,K=768) -------
// 32x64 tiles -> 192 blocks; wave computes 16x32 (acc[2]).
__global__ __launch_bounds__(256) void gemm_epilogue(
    const u16* __restrict__ aoh, const u16* __restrict__ aol,
    const u16* __restrict__ zh,  const u16* __restrict__ zl,
    const u16* __restrict__ BTh, const u16* __restrict__ BTl,
    const float* __restrict__ bo, const float* __restrict__ bp,
    float* __restrict__ C)
{
    __shared__ u16 As[2][32][68];
    __shared__ u16 Bs[2][64][68];
    const int tid = threadIdx.x;
    const int bm = blockIdx.y * 32, bn = blockIdx.x * 64;
    const int lane = tid & 63, wave = tid >> 6;
    const int m16 = lane & 15, quad = lane >> 4;
    const int wm = (wave >> 1) * 16, wn = (wave & 1) * 32;
    const int ra = tid >> 3, c8 = (tid & 7) * 8;
    const int rb = tid >> 2, c16 = (tid & 3) * 16;
    const int N = 512, K = 768;

    floatx4 acc[2];
    acc[0] = (floatx4){0.f, 0.f, 0.f, 0.f};
    acc[1] = (floatx4){0.f, 0.f, 0.f, 0.f};

    for (int k0 = 0; k0 < K; k0 += 64) {
        __syncthreads();
        const u16* pah;
        const u16* pal;
        if (k0 < 512) {
            pah = aoh + (size_t)(bm + ra) * 512 + k0 + c8;
            pal = aol + (size_t)(bm + ra) * 512 + k0 + c8;
        } else {
            pah = zh + (size_t)(bm + ra) * 256 + (k0 - 512) + c8;
            pal = zl + (size_t)(bm + ra) * 256 + (k0 - 512) + c8;
        }
        {
            uint4 v = *(const uint4*)pah;
            *(uint2*)&As[0][ra][c8 + 0] = make_uint2(v.x, v.y);
            *(uint2*)&As[0][ra][c8 + 4] = make_uint2(v.z, v.w);
            uint4 w = *(const uint4*)pal;
            *(uint2*)&As[1][ra][c8 + 0] = make_uint2(w.x, w.y);
            *(uint2*)&As[1][ra][c8 + 4] = make_uint2(w.z, w.w);
        }
        {
            const u16* pb = BTh + (size_t)(bn + rb) * K + k0 + c16;
            uint4 v0 = *(const uint4*)pb, v1 = *(const uint4*)(pb + 8);
            *(uint2*)&Bs[0][rb][c16 + 0]  = make_uint2(v0.x, v0.y);
            *(uint2*)&Bs[0][rb][c16 + 4]  = make_uint2(v0.z, v0.w);
            *(uint2*)&Bs[0][rb][c16 + 8]  = make_uint2(v1.x, v1.y);
            *(uint2*)&Bs[0][rb][c16 + 12] = make_uint2(v1.z, v1.w);
            const u16* pc = BTl + (size_t)(bn + rb) * K + k0 + c16;
            uint4 w0 = *(const uint4*)pc, w1 = *(const uint4*)(pc + 8);
            *(uint2*)&Bs[1][rb][c16 + 0]  = make_uint2(w0.x, w0.y);
            *(uint2*)&Bs[1][rb][c16 + 4]  = make_uint2(w0.z, w0.w);
            *(uint2*)&Bs[1][rb][c16 + 8]  = make_uint2(w1.x, w1.y);
            *(uint2*)&Bs[1][rb][c16 + 12] = make_uint2(w1.z, w1.w);
        }
        __syncthreads();
#pragma unroll
        for (int ks = 0; ks < 2; ++ks) {
            const int ko = ks * 32 + quad * 8;
            Frag ah = ld_frag8(&As[0][wm + m16][ko]);
            Frag al = ld_frag8(&As[1][wm + m16][ko]);
            Frag b0h = ld_frag8(&Bs[0][wn + m16][ko]);
            Frag b1h = ld_frag8(&Bs[0][wn + 16 + m16][ko]);
            Frag b0l = ld_frag8(&Bs[1][wn + m16][ko]);
            Frag b1l = ld_frag8(&Bs[1][wn + 16 + m16][ko]);
            acc[0] = mfma16(ah, b0h, acc[0]);
            acc[0] = mfma16(al, b0h, acc[0]);
            acc[0] = mfma16(ah, b0l, acc[0]);
            acc[1] = mfma16(ah, b1h, acc[1]);
            acc[1] = mfma16(al, b1h, acc[1]);
            acc[1] = mfma16(ah, b1l, acc[1]);
        }
    }
#pragma unroll
    for (int rr = 0; rr < 4; ++rr) {
        int m = bm + wm + quad * 4 + rr;
#pragma unroll
        for (int j = 0; j < 2; ++j) {
            int n = bn + wn + j * 16 + m16;
            C[(size_t)m * N + n] = acc[j][rr] + bo[n] + bp[n];
        }
    }
}

// ---------------- Flash-style MFMA attention ----------------
__global__ __launch_bounds__(256) void attn_mfma(
    const float* __restrict__ qkv, u16* __restrict__ aoh, u16* __restrict__ aol)
{
    __shared__ union { u16 Ks[192][68]; u16 P[64][196]; } KP;
    __shared__ u16 Vt[64][196];
    const int qt = blockIdx.x, h = blockIdx.y, b = blockIdx.z;
    const int tid = threadIdx.x;
    const int lane = tid & 63, wave = tid >> 6;
    const int m16 = lane & 15, quad = lane >> 4;
    const size_t base = (size_t)(b * T_) * 1536 + h * 64;

    for (int i = tid; i < 192 * 16; i += 256) {
        int row = i >> 4, c4 = (i & 15) << 2;
        float4 kv = *(const float4*)(qkv + base + (size_t)row * 1536 + 512 + c4);
        *(uint2*)&KP.Ks[row][c4] = make_uint2(pack_rne(kv.x, kv.y), pack_rne(kv.z, kv.w));
        float4 vv = *(const float4*)(qkv + base + (size_t)row * 1536 + 1024 + c4);
        Vt[c4 + 0][row] = bf16_rne(vv.x);
        Vt[c4 + 1][row] = bf16_rne(vv.y);
        Vt[c4 + 2][row] = bf16_rne(vv.z);
        Vt[c4 + 3][row] = bf16_rne(vv.w);
    }

    Frag qf0, qf1;
    {
        const float s = 0.125f * LOG2E;   // exp(x) = exp2(x*log2e), folded into q
        const float* qp = qkv + base + (size_t)(qt * 64 + wave * 16 + m16) * 1536 + quad * 8;
        float4 u0 = *(const float4*)qp;
        float4 u1 = *(const float4*)(qp + 4);
        float4 u2 = *(const float4*)(qp + 32);
        float4 u3 = *(const float4*)(qp + 36);
        qf0.i = (intx4){ (int)pack_rne(u0.x * s, u0.y * s), (int)pack_rne(u0.z * s, u0.w * s),
                         (int)pack_rne(u1.x * s, u1.y * s), (int)pack_rne(u1.z * s, u1.w * s) };
        qf1.i = (intx4){ (int)pack_rne(u2.x * s, u2.y * s), (int)pack_rne(u2.z * s, u2.w * s),
                         (int)pack_rne(u3.x * s, u3.y * s), (int)pack_rne(u3.z * s, u3.w * s) };
    }
    __syncthreads();

    float ev[12][4];
    float rsum[4] = {0.f, 0.f, 0.f, 0.f};
#pragma unroll
    for (int tt = 0; tt < 12; ++tt) {
        Frag kb0 = ld_frag8(&KP.Ks[tt * 16 + m16][quad * 8]);
        Frag kb1 = ld_frag8(&KP.Ks[tt * 16 + m16][32 + quad * 8]);
        floatx4 accs = (floatx4){0.f, 0.f, 0.f, 0.f};
        accs = mfma16(qf0, kb0, accs);
        accs = mfma16(qf1, kb1, accs);
#pragma unroll
        for (int rr = 0; rr < 4; ++rr) {
            float e = fexp2(accs[rr]);
            ev[tt][rr] = e;
            rsum[rr] += e;
        }
    }
#pragma unroll
    for (int rr = 0; rr < 4; ++rr) {
        float v = rsum[rr];
        v += __shfl_xor(v, 1, 64);
        v += __shfl_xor(v, 2, 64);
        v += __shfl_xor(v, 4, 64);
        v += __shfl_xor(v, 8, 64);
        rsum[rr] = 1.0f / v;
    }

    __syncthreads();
#pragma unroll
    for (int tt = 0; tt < 12; ++tt)
#pragma unroll
        for (int rr = 0; rr < 4; ++rr)
            KP.P[wave * 16 + quad * 4 + rr][tt * 16 + m16] = bf16_rne(ev[tt][rr]);

    floatx4 acco[4];
#pragma unroll
    for (int dt = 0; dt < 4; ++dt) acco[dt] = (floatx4){0.f, 0.f, 0.f, 0.f};
#pragma unroll
    for (int ts = 0; ts < 6; ++ts) {
        Frag pf = ld_frag8(&KP.P[wave * 16 + m16][ts * 32 + quad * 8]);
#pragma unroll
        for (int dt = 0; dt < 4; ++dt) {
            Frag vf = ld_frag8(&Vt[dt * 16 + m16][ts * 32 + quad * 8]);
            acco[dt] = mfma16(pf, vf, acco[dt]);
        }
    }
#pragma unroll
    for (int dt = 0; dt < 4; ++dt)
#pragma unroll
        for (int rr = 0; rr < 4; ++rr) {
            float o = acco[dt][rr] * rsum[rr];
            size_t idx = (size_t)(b * T_ + qt * 64 + wave * 16 + quad * 4 + rr) * 512
                       + h * 64 + dt * 16 + m16;
            u16 hi = bf16_rne(o);
            aoh[idx] = hi;
            aol[idx] = bf16_rne(o - bf16f(hi));
        }
}

// ---------------- Trittention cubic scores via MFMA -> rs, rt (partials) ----------------
// Round-4 optimum structure; log2e folded into a-quant; raw v_exp_f32 via builtin.
__global__ __launch_bounds__(256, 3) void tritt_score_mfma(
    const float* __restrict__ proj, float* __restrict__ rs_g, float* __restrict__ rt_g)
{
    __shared__ u32 a_lds[96 * 36];
    __shared__ u32 b_lds[48 * 36];
    __shared__ float rs_lds[96][32];
    __shared__ float rt_lds[48][32];

    const int h = blockIdx.y, b = blockIdx.z;
    const int qt = blockIdx.x >> 3;          // 0..5
    const int sc = (blockIdx.x >> 2) & 1;    // 0..1
    const int tc = blockIdx.x & 3;           // 0..3
    const int q0 = qt * 32, s0 = sc * 96, t0 = tc * 48;
    const int tid  = threadIdx.x;
    const int lane = tid & 63, wave = tid >> 6;
    const int m16  = lane & 15, quad = lane >> 4;
    const int bh = b * CH + h;
    const size_t rowbase = (size_t)(b * T_) * 1280 + h * 64;
    const float kA = 0.015625f * LOG2E;   // 1/64 * log2e folded into a's bf16

    for (int i = tid; i < 96 * 32; i += 256) {
        int row = i >> 5, cp = i & 31;
        const float2 va = *(const float2*)(proj + rowbase + (size_t)(s0 + row) * 1280 + 0 + cp * 2);
        a_lds[row * 36 + cp] = pack_rne(va.x * kA, va.y * kA);
        if (i < 48 * 32) {
            const float2 vb = *(const float2*)(proj + rowbase + (size_t)(t0 + row) * 1280 + 256 + cp * 2);
            b_lds[row * 36 + cp] = pack_rne(vb.x, vb.y);
        }
    }

    Frag cf[2][2];
#pragma unroll
    for (int jq = 0; jq < 2; ++jq) {
        const float* cp = proj + rowbase + (size_t)(q0 + jq * 16 + m16) * 1280 + 512 + quad * 8;
        float4 u0 = *(const float4*)(cp);
        float4 u1 = *(const float4*)(cp + 4);
        float4 u2 = *(const float4*)(cp + 32);
        float4 u3 = *(const float4*)(cp + 36);
        cf[jq][0].i = (intx4){ (int)pack_rne(u0.x, u0.y), (int)pack_rne(u0.z, u0.w),
                               (int)pack_rne(u1.x, u1.y), (int)pack_rne(u1.z, u1.w) };
        cf[jq][1].i = (intx4){ (int)pack_rne(u2.x, u2.y), (int)pack_rne(u2.z, u2.w),
                               (int)pack_rne(u3.x, u3.y), (int)pack_rne(u3.z, u3.w) };
    }
    __syncthreads();

    float rt_acc[3][4][2] = {};

    for (int si = 0; si < 24; ++si) {
        const int srow = wave * 24 + si;
        f32x2 af2[8];
        {
            intx4 av0 = *(const intx4*)(a_lds + srow * 36 + quad * 4);
            intx4 av1 = *(const intx4*)(a_lds + srow * 36 + 16 + quad * 4);
#pragma unroll
            for (int j = 0; j < 4; ++j) {
                u32 d0 = (u32)av0[j];
                af2[j] = (f32x2){ __uint_as_float(d0 << 16), __uint_as_float(d0 & 0xffff0000u) };
                u32 d1 = (u32)av1[j];
                af2[4 + j] = (f32x2){ __uint_as_float(d1 << 16), __uint_as_float(d1 & 0xffff0000u) };
            }
        }
        float rs_s[2] = {0.f, 0.f};
#pragma unroll
        for (int tt = 0; tt < 3; ++tt) {
            const u32* bp = b_lds + (tt * 16 + m16) * 36;
            intx4 bv0 = *(const intx4*)(bp + quad * 4);
            intx4 bv1 = *(const intx4*)(bp + 16 + quad * 4);
            Frag w0, w1;
#pragma unroll
            for (int j = 0; j < 4; ++j) {
                u32 d0 = (u32)bv0[j];
                f32x2 p0 = af2[j] * (f32x2){ __uint_as_float(d0 << 16),
                                             __uint_as_float(d0 & 0xffff0000u) };
                w0.i[j] = (int)__builtin_amdgcn_perm(__float_as_uint(p0.y),
                                                     __float_as_uint(p0.x), 0x07060302u);
                u32 d1 = (u32)bv1[j];
                f32x2 p1 = af2[4 + j] * (f32x2){ __uint_as_float(d1 << 16),
                                                 __uint_as_float(d1 & 0xffff0000u) };
                w1.i[j] = (int)__builtin_amdgcn_perm(__float_as_uint(p1.y),
                                                     __float_as_uint(p1.x), 0x07060302u);
            }
#pragma unroll
            for (int jq = 0; jq < 2; ++jq) {
                floatx4 acc = (floatx4){0.f, 0.f, 0.f, 0.f};
                acc = mfma16(w0, cf[jq][0], acc);
                acc = mfma16(w1, cf[jq][1], acc);
                // lane holds E[t_local = tt*16 + quad*4 + rr][q = q0 + jq*16 + m16]
#pragma unroll
                for (int rr = 0; rr < 4; ++rr) {
                    float e = fexp2(acc[rr]);
                    rt_acc[tt][rr][jq] += e;
                    rs_s[jq] += e;
                }
            }
        }
#pragma unroll
        for (int jq = 0; jq < 2; ++jq) {
            float v = rs_s[jq];
            v += __shfl_xor(v, 16, 64);
            v += __shfl_xor(v, 32, 64);
            if (lane < 16) rs_lds[srow][jq * 16 + m16] = v;
        }
    }

    __syncthreads();
    for (int w = 0; w < 4; ++w) {
        if (wave == w) {
#pragma unroll
            for (int tt = 0; tt < 3; ++tt)
#pragma unroll
                for (int rr = 0; rr < 4; ++rr) {
                    int t = tt * 16 + quad * 4 + rr;
#pragma unroll
                    for (int jq = 0; jq < 2; ++jq) {
                        if (w == 0) rt_lds[t][jq * 16 + m16] = rt_acc[tt][rr][jq];
                        else        rt_lds[t][jq * 16 + m16] += rt_acc[tt][rr][jq];
                    }
                }
        }
        __syncthreads();
    }
    for (int i = tid; i < 32 * 96; i += 256) {
        int qq = i / 96, ss = i % 96;
        rs_g[((size_t)(tc * 16 + bh) * T_ + q0 + qq) * T_ + s0 + ss] = rs_lds[ss][qq];
    }
    for (int i = tid; i < 32 * 48; i += 256) {
        int qq = i / 48, t2 = i % 48;
        rt_g[((size_t)(sc * 16 + bh) * T_ + q0 + qq) * T_ + t0 + t2] = rt_lds[t2][qq];
    }
}

// ------- zgemm: z[q][d] = ( [rs|rt] @ DE^T ) / Z  per bh; d split across 2 blocks -------
__global__ __launch_bounds__(256) void zgemm(
    const float* __restrict__ rs_g, const float* __restrict__ rt_g,
    const float* __restrict__ proj, u16* __restrict__ zzh, u16* __restrict__ zzl)
{
    __shared__ u16 As[2][64][68];
    __shared__ u16 Bs[32][68];
    __shared__ float zred[64][4];
    __shared__ float Zl[64];
    const int mt = blockIdx.x >> 1, dh2 = blockIdx.x & 1, bh = blockIdx.y;
    const int b = bh >> 2, h = bh & 3;
    const int q0 = mt * 64;
    const int tid = threadIdx.x;
    const int lane = tid & 63, wave = tid >> 6;
    const int m16 = lane & 15, quad = lane >> 4;
    const int wm = (wave >> 1) * 32, wn = (wave & 1) * 16;
    const int r = tid >> 2, c16 = (tid & 3) * 16;

    {
        float zp = 0.f;
        const int j = tid & 3;
#pragma unroll
        for (int tc = 0; tc < 4; ++tc) {
            const float* p = rs_g + ((size_t)(tc * 16 + bh) * T_ + q0 + r) * T_ + j * 48;
#pragma unroll
            for (int s = 0; s < 48; s += 4) {
                float4 v = *(const float4*)(p + s);
                zp += (v.x + v.y) + (v.z + v.w);
            }
        }
        zred[r][j] = zp;
    }
    __syncthreads();
    if (tid < 64)
        Zl[tid] = 1.0f / (zred[tid][0] + zred[tid][1] + zred[tid][2] + zred[tid][3]);

    floatx4 acc[2];
    acc[0] = (floatx4){0.f, 0.f, 0.f, 0.f};
    acc[1] = (floatx4){0.f, 0.f, 0.f, 0.f};

    for (int k0 = 0; k0 < 384; k0 += 64) {
        __syncthreads();
        {   // G staging: sum partials, pack hi/lo
            float g[16];
#pragma unroll
            for (int i = 0; i < 16; ++i) g[i] = 0.f;
            if (k0 < 192) {
#pragma unroll
                for (int tc = 0; tc < 4; ++tc) {
                    const float* p = rs_g + ((size_t)(tc * 16 + bh) * T_ + q0 + r) * T_ + k0 + c16;
#pragma unroll
                    for (int i = 0; i < 16; i += 4) {
                        float4 v = *(const float4*)(p + i);
                        g[i] += v.x; g[i + 1] += v.y; g[i + 2] += v.z; g[i + 3] += v.w;
                    }
                }
            } else {
#pragma unroll
                for (int sc = 0; sc < 2; ++sc) {
                    const float* p = rt_g + ((size_t)(sc * 16 + bh) * T_ + q0 + r) * T_ + (k0 - 192) + c16;
#pragma unroll
                    for (int i = 0; i < 16; i += 4) {
                        float4 v = *(const float4*)(p + i);
                        g[i] += v.x; g[i + 1] += v.y; g[i + 2] += v.z; g[i + 3] += v.w;
                    }
                }
            }
#pragma unroll
            for (int i = 0; i < 16; ++i) {
                u16 hi = bf16_rne(g[i]);
                As[0][r][c16 + i] = hi;
                As[1][r][c16 + i] = bf16_rne(g[i] - bf16f(hi));
            }
        }
        {   // DE^T staging from proj: Bs[d_local][s_local], 32 d-cols for this d-half
            const int colbase = (k0 < 192 ? 768 : 1024) + h * 64 + dh2 * 32;
            const int s0 = (k0 < 192 ? k0 : k0 - 192);
            const int sl = tid >> 2;          // 0..63
            const int d4b = (tid & 3) * 4;    // 0..12
#pragma unroll
            for (int i = 0; i < 2; ++i) {
                int dd = d4b + i * 16;        // 0..28
                float4 v = *(const float4*)(proj + (size_t)(b * T_ + s0 + sl) * 1280 + colbase + dd);
                Bs[dd + 0][sl] = bf16_rne(v.x);
                Bs[dd + 1][sl] = bf16_rne(v.y);
                Bs[dd + 2][sl] = bf16_rne(v.z);
                Bs[dd + 3][sl] = bf16_rne(v.w);
            }
        }
        __syncthreads();
#pragma unroll
        for (int ks = 0; ks < 2; ++ks) {
            const int ko = ks * 32 + quad * 8;
            Frag g0h = ld_frag8(&As[0][wm + m16][ko]);
            Frag g1h = ld_frag8(&As[0][wm + 16 + m16][ko]);
            Frag g0l = ld_frag8(&As[1][wm + m16][ko]);
            Frag g1l = ld_frag8(&As[1][wm + 16 + m16][ko]);
            Frag d0 = ld_frag8(&Bs[wn + m16][ko]);
            acc[0] = mfma16(g0h, d0, acc[0]);
            acc[0] = mfma16(g0l, d0, acc[0]);
            acc[1] = mfma16(g1h, d0, acc[1]);
            acc[1] = mfma16(g1l, d0, acc[1]);
        }
    }
#pragma unroll
    for (int i = 0; i < 2; ++i)
#pragma unroll
        for (int rr = 0; rr < 4; ++rr) {
            int m = wm + i * 16 + quad * 4 + rr;
            int d = dh2 * 32 + wn + m16;
            float zv = acc[i][rr] * Zl[m];
            size_t idx = (size_t)(b * T_ + q0 + m) * 256 + h * 64 + d;
            u16 hi = bf16_rne(zv);
            zzh[idx] = hi;
            zzl[idx] = bf16_rne(zv - bf16f(hi));
        }
}

extern "C" void kernel_launch(void* const* d_in, const int* in_sizes, int n_in,
                              void* d_out, int out_size, void* d_ws, size_t ws_size,
                              hipStream_t stream)
{
    const float* x      = (const float*)d_in[0];
    const float* ln1_g  = (const float*)d_in[1];
    const float* ln1_b  = (const float*)d_in[2];
    const float* Wqkv   = (const float*)d_in[3];
    const float* Wo     = (const float*)d_in[4];
    const float* bo     = (const float*)d_in[5];
    const float* ln2_g  = (const float*)d_in[6];
    const float* ln2_b  = (const float*)d_in[7];
    const float* Wabcde = (const float*)d_in[8];
    const float* babcde = (const float*)d_in[9];
    const float* Wp     = (const float*)d_in[10];
    const float* bp     = (const float*)d_in[11];
    float* out = (float*)d_out;

    // ---- workspace layout (f32 units), total 6,684,672 f = 25.5 MiB ----
    float* ws   = (float*)d_ws;
    float* proj = ws;                              // 983,040 f (alive through zgemm)
    u16* wofh   = (u16*)(proj + 983040);           // 512*768 hi/lo = 393,216 f
    u16* wofl   = wofh + 393216;
    u16* aoh    = (u16*)(ws + 1376256);            // 768*512 hi/lo = 393,216 f
    u16* aol    = aoh + 393216;
    u16* zh     = (u16*)(ws + 1769472);            // z hi/lo = 196,608 f
    u16* zl     = zh + 196608;
    float* rs   = ws + 1966080;                    // 4 tc-partials: 2,359,296 f
    float* rt   = rs + 2359296;                    // 2 sc-partials used (region 2,359,296 f)
    // aliases (disjoint lifetimes):
    float* qkv = rs;                               // dead before rs written
    u16* x1h = (u16*)(rs + 1179648);               // x bufs in rs tail
    u16* x1l = x1h + 393216;
    u16* x2h = x1l + 393216;
    u16* x2l = x2h + 393216;
    u16* wqh = (u16*)rt;                           // Wqkv^T in rt head (dead before rt written)
    u16* wql = wqh + 786432;
    u16* wah = (u16*)(rt + 786432);                // Wabcde^T in rt tail (dead before tritt)
    u16* wal = wah + 655360;

    prep_kernel<<<1216, 256, 0, stream>>>(x, ln1_g, ln1_b, ln2_g, ln2_b,
                                          x1h, x1l, x2h, x2l,
                                          Wqkv, wqh, wql, Wabcde, wah, wal,
                                          Wo, Wp, wofh, wofl);
    gemm_dual<<<dim3(44, 12), 256, 0, stream>>>(x1h, x1l, wqh, wql, x2h, x2l, wah, wal,
                                                babcde, qkv, proj);
    attn_mfma<<<dim3(3, AH, B_), 256, 0, stream>>>(qkv, aoh, aol);
    tritt_score_mfma<<<dim3(48, CH, B_), 256, 0, stream>>>(proj, rs, rt);
    zgemm<<<dim3(6, 16), 256, 0, stream>>>(rs, rt, proj, zh, zl);
    gemm_epilogue<<<dim3(8, 24), 256, 0, stream>>>(aoh, aol, zh, zl, wofh, wofl, bo, bp, out);
}

// Round 13
// 179.308 us; speedup vs baseline: 1.0945x; 1.0241x over previous
//
#include <hip/hip_runtime.h>
#include <cstdint>

// MixedAttention: attention (8 heads) + trittention (4 heads, cubic scores), T=192, DIM=512.
// Round 12: gemm_dual 2-pass split (C = Ah*Bh + Al*Bh; weights plain bf16, activations
// hi/lo). Drops 1/3 of MFMAs + Bl staging; LDS 69.6->52.2KB = 3 blocks/CU (was 2). prep no
// longer writes wql/wal. Error budget: weights-bf16 adds ~4e-4 at out (quadrature with
// 4.9e-4 -> ~1e-3 < 1.61e-3 threshold). Epilogue stays 3-pass. tritt untouched (51.2us).

#define B_   4
#define T_   192
#define DIM_ 512
#define AH   8
#define CH   4

typedef unsigned short u16;
typedef unsigned int   u32;
typedef __attribute__((ext_vector_type(8))) short short8;
typedef __attribute__((ext_vector_type(4))) float floatx4;
typedef __attribute__((ext_vector_type(4))) int intx4;
typedef __attribute__((ext_vector_type(2))) float f32x2;

union Frag { intx4 i; short8 s; };

__device__ __forceinline__ floatx4 mfma16(Frag a, Frag b, floatx4 c) {
    return __builtin_amdgcn_mfma_f32_16x16x32_bf16(a.s, b.s, c, 0, 0, 0);
}

__device__ __forceinline__ float fexp2(float x) {
    return __builtin_amdgcn_exp2f(x);   // bare v_exp_f32
}

__device__ __forceinline__ float wave_reduce_sum(float v) {
#pragma unroll
    for (int off = 32; off >= 1; off >>= 1)
        v += __shfl_xor(v, off, 64);
    return v;
}

__device__ __forceinline__ u32 pack_rne(float x, float y) {
    u32 ux = __float_as_uint(x);
    u32 uy = __float_as_uint(y);
    ux += 0x7fffu + ((ux >> 16) & 1u);
    uy += 0x7fffu + ((uy >> 16) & 1u);
    return (ux >> 16) | (uy & 0xffff0000u);
}
__device__ __forceinline__ u16 bf16_rne(float x) {
    u32 u = __float_as_uint(x);
    u += 0x7fffu + ((u >> 16) & 1u);
    return (u16)(u >> 16);
}
__device__ __forceinline__ float bf16f(u16 h) { return __uint_as_float(((u32)h) << 16); }

__device__ __forceinline__ Frag ld_frag8(const u16* p) {
    Frag f;
    uint2 a = *(const uint2*)p;
    uint2 b = *(const uint2*)(p + 4);
    f.i = (intx4){ (int)a.x, (int)a.y, (int)b.x, (int)b.y };
    return f;
}

#define LOG2E 1.44269504088896f

// ---------------- Fused prep: LayerNorm (blocks 0..767) + weight transpose (768..1215) ------
// Wqkv/Wab: hi only (2-pass gemm_dual). Wo/Wp stacked: hi+lo (3-pass epilogue).
__global__ __launch_bounds__(256) void prep_kernel(
    const float* __restrict__ x,
    const float* __restrict__ g1, const float* __restrict__ b1,
    const float* __restrict__ g2, const float* __restrict__ b2,
    u16* __restrict__ x1h, u16* __restrict__ x1l,
    u16* __restrict__ x2h, u16* __restrict__ x2l,
    const float* __restrict__ Wqkv, u16* __restrict__ wqh,
    const float* __restrict__ Wab,  u16* __restrict__ wah,
    const float* __restrict__ Wo,   const float* __restrict__ Wp,
    u16* __restrict__ wofh, u16* __restrict__ wofl)
{
    __shared__ union { float t[64][65]; float red[4][2]; } u;
    const int tid = threadIdx.x;
    if (blockIdx.x < 768) {
        int row = blockIdx.x;
        const float2 v = ((const float2*)(x + (size_t)row * DIM_))[tid];
        float s  = v.x + v.y;
        float s2 = v.x * v.x + v.y * v.y;
        s  = wave_reduce_sum(s);
        s2 = wave_reduce_sum(s2);
        int w = tid >> 6;
        if ((tid & 63) == 0) { u.red[w][0] = s; u.red[w][1] = s2; }
        __syncthreads();
        float ts  = u.red[0][0] + u.red[1][0] + u.red[2][0] + u.red[3][0];
        float ts2 = u.red[0][1] + u.red[1][1] + u.red[2][1] + u.red[3][1];
        float mean = ts * (1.0f / DIM_);
        float var  = ts2 * (1.0f / DIM_) - mean * mean;
        float rstd = rsqrtf(var + 1e-5f);
        int c0 = tid * 2;
        float n0 = (v.x - mean) * rstd;
        float n1 = (v.y - mean) * rstd;
        float a0 = n0 * g1[c0] + b1[c0], a1 = n1 * g1[c0 + 1] + b1[c0 + 1];
        float c2 = n0 * g2[c0] + b2[c0], c3 = n1 * g2[c0 + 1] + b2[c0 + 1];
        u16 h0 = bf16_rne(a0), h1 = bf16_rne(a1);
        u16 h2 = bf16_rne(c2), h3 = bf16_rne(c3);
        u16 l0 = bf16_rne(a0 - bf16f(h0)), l1 = bf16_rne(a1 - bf16f(h1));
        u16 l2 = bf16_rne(c2 - bf16f(h2)), l3 = bf16_rne(c3 - bf16f(h3));
        size_t o = (size_t)row * 256 + tid;
        ((u32*)x1h)[o] = (u32)h0 | ((u32)h1 << 16);
        ((u32*)x1l)[o] = (u32)l0 | ((u32)l1 << 16);
        ((u32*)x2h)[o] = (u32)h2 | ((u32)h3 << 16);
        ((u32*)x2l)[o] = (u32)l2 | ((u32)l3 << 16);
        return;
    }
    int id = blockIdx.x - 768;
    const float* W; u16 *H, *L; int K, N, Kout, kofs, tile, wantLo;
    if (id < 192)      { W = Wqkv; H = wqh;  L = nullptr; K = 512; N = 1536; Kout = 512; kofs = 0;   tile = id;       wantLo = 0; }
    else if (id < 352) { W = Wab;  H = wah;  L = nullptr; K = 512; N = 1280; Kout = 512; kofs = 0;   tile = id - 192; wantLo = 0; }
    else if (id < 416) { W = Wo;   H = wofh; L = wofl;    K = 512; N = 512;  Kout = 768; kofs = 0;   tile = id - 352; wantLo = 1; }
    else               { W = Wp;   H = wofh; L = wofl;    K = 256; N = 512;  Kout = 768; kofs = 512; tile = id - 416; wantLo = 1; }
    int nx = N >> 6;
    int n0 = (tile % nx) * 64, k0 = (tile / nx) * 64;
    int rr = tid >> 4, c4 = (tid & 15) << 2;
#pragma unroll
    for (int p = 0; p < 4; ++p) {
        int row = rr + p * 16;
        float4 v = *(const float4*)(W + (size_t)(k0 + row) * N + n0 + c4);
        u.t[row][c4 + 0] = v.x; u.t[row][c4 + 1] = v.y;
        u.t[row][c4 + 2] = v.z; u.t[row][c4 + 3] = v.w;
    }
    __syncthreads();
#pragma unroll
    for (int p = 0; p < 4; ++p) {
        int n = rr + p * 16;
        u16 hi[4], lo[4];
#pragma unroll
        for (int c = 0; c < 4; ++c) {
            float v = u.t[c4 + c][n];
            hi[c] = bf16_rne(v);
            lo[c] = bf16_rne(v - bf16f(hi[c]));
        }
        size_t o = (size_t)(n0 + n) * Kout + kofs + k0 + c4;
        *(uint2*)&H[o] = make_uint2((u32)hi[0] | ((u32)hi[1] << 16), (u32)hi[2] | ((u32)hi[3] << 16));
        if (wantLo)
            *(uint2*)&L[o] = make_uint2((u32)lo[0] | ((u32)lo[1] << 16), (u32)lo[2] | ((u32)lo[3] << 16));
    }
}

// ------- Block-diagonal fused input GEMMs (2-pass): C = (Ah+Al) @ Bh^T (+bias) -------
// A = LN activations hi/lo (fp32-grade); B = weights plain bf16. LDS 52.2KB -> 3 blocks/CU.
__global__ __launch_bounds__(256) void gemm_dual(
    const u16* __restrict__ x1h, const u16* __restrict__ x1l,
    const u16* __restrict__ wqh,
    const u16* __restrict__ x2h, const u16* __restrict__ x2l,
    const u16* __restrict__ wah,
    const float* __restrict__ babcde,
    float* __restrict__ qkv, float* __restrict__ proj)
{
    __shared__ u16 As[2][64][68];
    __shared__ u16 Bs[64][68];
    const int tid = threadIdx.x;
    const int nb = blockIdx.x;
    const u16 *Ah, *Al, *BTh; const float* bias; float* C; int N, bn;
    if (nb < 24) { Ah = x1h; Al = x1l; BTh = wqh; bias = nullptr; C = qkv;  N = 1536; bn = nb * 64; }
    else         { Ah = x2h; Al = x2l; BTh = wah; bias = babcde; C = proj; N = 1280; bn = (nb - 24) * 64; }
    const int K = 512;
    const int bm = blockIdx.y * 64;
    const int lane = tid & 63, wave = tid >> 6;
    const int m16 = lane & 15, quad = lane >> 4;
    const int wm = (wave >> 1) * 32, wn = (wave & 1) * 32;
    const int r = tid >> 2, c16 = (tid & 3) * 16;

    floatx4 acc[2][2];
#pragma unroll
    for (int i = 0; i < 2; ++i)
#pragma unroll
        for (int j = 0; j < 2; ++j) acc[i][j] = (floatx4){0.f, 0.f, 0.f, 0.f};

    for (int k0 = 0; k0 < K; k0 += 64) {
        __syncthreads();
        {
            const u16* pa = Ah + (size_t)(bm + r) * K + k0 + c16;
            uint4 v0 = *(const uint4*)pa, v1 = *(const uint4*)(pa + 8);
            *(uint2*)&As[0][r][c16 + 0]  = make_uint2(v0.x, v0.y);
            *(uint2*)&As[0][r][c16 + 4]  = make_uint2(v0.z, v0.w);
            *(uint2*)&As[0][r][c16 + 8]  = make_uint2(v1.x, v1.y);
            *(uint2*)&As[0][r][c16 + 12] = make_uint2(v1.z, v1.w);
            const u16* pl = Al + (size_t)(bm + r) * K + k0 + c16;
            uint4 w0 = *(const uint4*)pl, w1 = *(const uint4*)(pl + 8);
            *(uint2*)&As[1][r][c16 + 0]  = make_uint2(w0.x, w0.y);
            *(uint2*)&As[1][r][c16 + 4]  = make_uint2(w0.z, w0.w);
            *(uint2*)&As[1][r][c16 + 8]  = make_uint2(w1.x, w1.y);
            *(uint2*)&As[1][r][c16 + 12] = make_uint2(w1.z, w1.w);
        }
        {
            const u16* pb = BTh + (size_t)(bn + r) * K + k0 + c16;
            uint4 v0 = *(const uint4*)pb, v1 = *(const uint4*)(pb + 8);
            *(uint2*)&Bs[r][c16 + 0]  = make_uint2(v0.x, v0.y);
            *(uint2*)&Bs[r][c16 + 4]  = make_uint2(v0.z, v0.w);
            *(uint2*)&Bs[r][c16 + 8]  = make_uint2(v1.x, v1.y);
            *(uint2*)&Bs[r][c16 + 12] = make_uint2(v1.z, v1.w);
        }
        __syncthreads();
#pragma unroll
        for (int ks = 0; ks < 2; ++ks) {
            const int ko = ks * 32 + quad * 8;
            Frag a0h = ld_frag8(&As[0][wm + m16][ko]);
            Frag a1h = ld_frag8(&As[0][wm + 16 + m16][ko]);
            Frag a0l = ld_frag8(&As[1][wm + m16][ko]);
            Frag a1l = ld_frag8(&As[1][wm + 16 + m16][ko]);
            Frag b0 = ld_frag8(&Bs[wn + m16][ko]);
            Frag b1 = ld_frag8(&Bs[wn + 16 + m16][ko]);
            acc[0][0] = mfma16(a0h, b0, acc[0][0]);
            acc[0][0] = mfma16(a0l, b0, acc[0][0]);
            acc[0][1] = mfma16(a0h, b1, acc[0][1]);
            acc[0][1] = mfma16(a0l, b1, acc[0][1]);
            acc[1][0] = mfma16(a1h, b0, acc[1][0]);
            acc[1][0] = mfma16(a1l, b0, acc[1][0]);
            acc[1][1] = mfma16(a1h, b1, acc[1][1]);
            acc[1][1] = mfma16(a1l, b1, acc[1][1]);
        }
    }
#pragma unroll
    for (int i = 0; i < 2; ++i)
#pragma unroll
        for (int rr = 0; rr < 4; ++rr) {
            int m = bm + wm + i * 16 + quad * 4 + rr;
#pragma unroll
            for (int j = 0; j < 2; ++j) {
                int n = bn + wn + j * 16 + m16;
                float v = acc[i][j][rr];
                if (bias) v += bias[n];
                C[(size_t)m * N + n] = v;
            }
        }
}

// ------- Fused epilogue GEMM: out = [ao | z] @ [Wo;Wp]^T + bo + bp  (M=768,N=512,K=768) -------
// 32x64 tiles -> 192 blocks; wave computes 16x32 (acc[2]). 3-pass (weights hi/lo).
__global__ __launch_bounds__(256) void gemm_epilogue(
    const u16* __restrict__ aoh, const u16* __restrict__ aol,
    const u16* __restrict__ zh,  const u16* __restrict__ zl,
    const u16* __restrict__ BTh, const u16* __restrict__ BTl,
    const float* __restrict__ bo, const float* __restrict__ bp,
    float* __restrict__ C)
{
    __shared__ u16 As[2][32][68];
    __shared__ u16 Bs[2][64][68];
    const int tid = threadIdx.x;
    const int bm = blockIdx.y * 32, bn = blockIdx.x * 64;
    const int lane = tid & 63, wave = tid >> 6;
    const int m16 = lane & 15, quad = lane >> 4;
    const int wm = (wave >> 1) * 16, wn = (wave & 1) * 32;
    const int ra = tid >> 3, c8 = (tid & 7) * 8;
    const int rb = tid >> 2, c16 = (tid & 3) * 16;
    const int N = 512, K = 768;

    floatx4 acc[2];
    acc[0] = (floatx4){0.f, 0.f, 0.f, 0.f};
    acc[1] = (floatx4){0.f, 0.f, 0.f, 0.f};

    for (int k0 = 0; k0 < K; k0 += 64) {
        __syncthreads();
        const u16* pah;
        const u16* pal;
        if (k0 < 512) {
            pah = aoh + (size_t)(bm + ra) * 512 + k0 + c8;
            pal = aol + (size_t)(bm + ra) * 512 + k0 + c8;
        } else {
            pah = zh + (size_t)(bm + ra) * 256 + (k0 - 512) + c8;
            pal = zl + (size_t)(bm + ra) * 256 + (k0 - 512) + c8;
        }
        {
            uint4 v = *(const uint4*)pah;
            *(uint2*)&As[0][ra][c8 + 0] = make_uint2(v.x, v.y);
            *(uint2*)&As[0][ra][c8 + 4] = make_uint2(v.z, v.w);
            uint4 w = *(const uint4*)pal;
            *(uint2*)&As[1][ra][c8 + 0] = make_uint2(w.x, w.y);
            *(uint2*)&As[1][ra][c8 + 4] = make_uint2(w.z, w.w);
        }
        {
            const u16* pb = BTh + (size_t)(bn + rb) * K + k0 + c16;
            uint4 v0 = *(const uint4*)pb, v1 = *(const uint4*)(pb + 8);
            *(uint2*)&Bs[0][rb][c16 + 0]  = make_uint2(v0.x, v0.y);
            *(uint2*)&Bs[0][rb][c16 + 4]  = make_uint2(v0.z, v0.w);
            *(uint2*)&Bs[0][rb][c16 + 8]  = make_uint2(v1.x, v1.y);
            *(uint2*)&Bs[0][rb][c16 + 12] = make_uint2(v1.z, v1.w);
            const u16* pc = BTl + (size_t)(bn + rb) * K + k0 + c16;
            uint4 w0 = *(const uint4*)pc, w1 = *(const uint4*)(pc + 8);
            *(uint2*)&Bs[1][rb][c16 + 0]  = make_uint2(w0.x, w0.y);
            *(uint2*)&Bs[1][rb][c16 + 4]  = make_uint2(w0.z, w0.w);
            *(uint2*)&Bs[1][rb][c16 + 8]  = make_uint2(w1.x, w1.y);
            *(uint2*)&Bs[1][rb][c16 + 12] = make_uint2(w1.z, w1.w);
        }
        __syncthreads();
#pragma unroll
        for (int ks = 0; ks < 2; ++ks) {
            const int ko = ks * 32 + quad * 8;
            Frag ah = ld_frag8(&As[0][wm + m16][ko]);
            Frag al = ld_frag8(&As[1][wm + m16][ko]);
            Frag b0h = ld_frag8(&Bs[0][wn + m16][ko]);
            Frag b1h = ld_frag8(&Bs[0][wn + 16 + m16][ko]);
            Frag b0l = ld_frag8(&Bs[1][wn + m16][ko]);
            Frag b1l = ld_frag8(&Bs[1][wn + 16 + m16][ko]);
            acc[0] = mfma16(ah, b0h, acc[0]);
            acc[0] = mfma16(al, b0h, acc[0]);
            acc[0] = mfma16(ah, b0l, acc[0]);
            acc[1] = mfma16(ah, b1h, acc[1]);
            acc[1] = mfma16(al, b1h, acc[1]);
            acc[1] = mfma16(ah, b1l, acc[1]);
        }
    }
#pragma unroll
    for (int rr = 0; rr < 4; ++rr) {
        int m = bm + wm + quad * 4 + rr;
#pragma unroll
        for (int j = 0; j < 2; ++j) {
            int n = bn + wn + j * 16 + m16;
            C[(size_t)m * N + n] = acc[j][rr] + bo[n] + bp[n];
        }
    }
}

// ---------------- Flash-style MFMA attention ----------------
__global__ __launch_bounds__(256) void attn_mfma(
    const float* __restrict__ qkv, u16* __restrict__ aoh, u16* __restrict__ aol)
{
    __shared__ union { u16 Ks[192][68]; u16 P[64][196]; } KP;
    __shared__ u16 Vt[64][196];
    const int qt = blockIdx.x, h = blockIdx.y, b = blockIdx.z;
    const int tid = threadIdx.x;
    const int lane = tid & 63, wave = tid >> 6;
    const int m16 = lane & 15, quad = lane >> 4;
    const size_t base = (size_t)(b * T_) * 1536 + h * 64;

    for (int i = tid; i < 192 * 16; i += 256) {
        int row = i >> 4, c4 = (i & 15) << 2;
        float4 kv = *(const float4*)(qkv + base + (size_t)row * 1536 + 512 + c4);
        *(uint2*)&KP.Ks[row][c4] = make_uint2(pack_rne(kv.x, kv.y), pack_rne(kv.z, kv.w));
        float4 vv = *(const float4*)(qkv + base + (size_t)row * 1536 + 1024 + c4);
        Vt[c4 + 0][row] = bf16_rne(vv.x);
        Vt[c4 + 1][row] = bf16_rne(vv.y);
        Vt[c4 + 2][row] = bf16_rne(vv.z);
        Vt[c4 + 3][row] = bf16_rne(vv.w);
    }

    Frag qf0, qf1;
    {
        const float s = 0.125f * LOG2E;
        const float* qp = qkv + base + (size_t)(qt * 64 + wave * 16 + m16) * 1536 + quad * 8;
        float4 u0 = *(const float4*)qp;
        float4 u1 = *(const float4*)(qp + 4);
        float4 u2 = *(const float4*)(qp + 32);
        float4 u3 = *(const float4*)(qp + 36);
        qf0.i = (intx4){ (int)pack_rne(u0.x * s, u0.y * s), (int)pack_rne(u0.z * s, u0.w * s),
                         (int)pack_rne(u1.x * s, u1.y * s), (int)pack_rne(u1.z * s, u1.w * s) };
        qf1.i = (intx4){ (int)pack_rne(u2.x * s, u2.y * s), (int)pack_rne(u2.z * s, u2.w * s),
                         (int)pack_rne(u3.x * s, u3.y * s), (int)pack_rne(u3.z * s, u3.w * s) };
    }
    __syncthreads();

    float ev[12][4];
    float rsum[4] = {0.f, 0.f, 0.f, 0.f};
#pragma unroll
    for (int tt = 0; tt < 12; ++tt) {
        Frag kb0 = ld_frag8(&KP.Ks[tt * 16 + m16][quad * 8]);
        Frag kb1 = ld_frag8(&KP.Ks[tt * 16 + m16][32 + quad * 8]);
        floatx4 accs = (floatx4){0.f, 0.f, 0.f, 0.f};
        accs = mfma16(qf0, kb0, accs);
        accs = mfma16(qf1, kb1, accs);
#pragma unroll
        for (int rr = 0; rr < 4; ++rr) {
            float e = fexp2(accs[rr]);
            ev[tt][rr] = e;
            rsum[rr] += e;
        }
    }
#pragma unroll
    for (int rr = 0; rr < 4; ++rr) {
        float v = rsum[rr];
        v += __shfl_xor(v, 1, 64);
        v += __shfl_xor(v, 2, 64);
        v += __shfl_xor(v, 4, 64);
        v += __shfl_xor(v, 8, 64);
        rsum[rr] = 1.0f / v;
    }

    __syncthreads();
#pragma unroll
    for (int tt = 0; tt < 12; ++tt)
#pragma unroll
        for (int rr = 0; rr < 4; ++rr)
            KP.P[wave * 16 + quad * 4 + rr][tt * 16 + m16] = bf16_rne(ev[tt][rr]);

    floatx4 acco[4];
#pragma unroll
    for (int dt = 0; dt < 4; ++dt) acco[dt] = (floatx4){0.f, 0.f, 0.f, 0.f};
#pragma unroll
    for (int ts = 0; ts < 6; ++ts) {
        Frag pf = ld_frag8(&KP.P[wave * 16 + m16][ts * 32 + quad * 8]);
#pragma unroll
        for (int dt = 0; dt < 4; ++dt) {
            Frag vf = ld_frag8(&Vt[dt * 16 + m16][ts * 32 + quad * 8]);
            acco[dt] = mfma16(pf, vf, acco[dt]);
        }
    }
#pragma unroll
    for (int dt = 0; dt < 4; ++dt)
#pragma unroll
        for (int rr = 0; rr < 4; ++rr) {
            float o = acco[dt][rr] * rsum[rr];
            size_t idx = (size_t)(b * T_ + qt * 64 + wave * 16 + quad * 4 + rr) * 512
                       + h * 64 + dt * 16 + m16;
            u16 hi = bf16_rne(o);
            aoh[idx] = hi;
            aol[idx] = bf16_rne(o - bf16f(hi));
        }
}

// ---------------- Trittention cubic scores via MFMA -> rs, rt (partials) ----------------
__global__ __launch_bounds__(256, 3) void tritt_score_mfma(
    const float* __restrict__ proj, float* __restrict__ rs_g, float* __restrict__ rt_g)
{
    __shared__ u32 a_lds[96 * 36];
    __shared__ u32 b_lds[48 * 36];
    __shared__ float rs_lds[96][32];
    __shared__ float rt_lds[48][32];

    const int h = blockIdx.y, b = blockIdx.z;
    const int qt = blockIdx.x >> 3;          // 0..5
    const int sc = (blockIdx.x >> 2) & 1;    // 0..1
    const int tc = blockIdx.x & 3;           // 0..3
    const int q0 = qt * 32, s0 = sc * 96, t0 = tc * 48;
    const int tid  = threadIdx.x;
    const int lane = tid & 63, wave = tid >> 6;
    const int m16  = lane & 15, quad = lane >> 4;
    const int bh = b * CH + h;
    const size_t rowbase = (size_t)(b * T_) * 1280 + h * 64;
    const float kA = 0.015625f * LOG2E;

    for (int i = tid; i < 96 * 32; i += 256) {
        int row = i >> 5, cp = i & 31;
        const float2 va = *(const float2*)(proj + rowbase + (size_t)(s0 + row) * 1280 + 0 + cp * 2);
        a_lds[row * 36 + cp] = pack_rne(va.x * kA, va.y * kA);
        if (i < 48 * 32) {
            const float2 vb = *(const float2*)(proj + rowbase + (size_t)(t0 + row) * 1280 + 256 + cp * 2);
            b_lds[row * 36 + cp] = pack_rne(vb.x, vb.y);
        }
    }

    Frag cf[2][2];
#pragma unroll
    for (int jq = 0; jq < 2; ++jq) {
        const float* cp = proj + rowbase + (size_t)(q0 + jq * 16 + m16) * 1280 + 512 + quad * 8;
        float4 u0 = *(const float4*)(cp);
        float4 u1 = *(const float4*)(cp + 4);
        float4 u2 = *(const float4*)(cp + 32);
        float4 u3 = *(const float4*)(cp + 36);
        cf[jq][0].i = (intx4){ (int)pack_rne(u0.x, u0.y), (int)pack_rne(u0.z, u0.w),
                               (int)pack_rne(u1.x, u1.y), (int)pack_rne(u1.z, u1.w) };
        cf[jq][1].i = (intx4){ (int)pack_rne(u2.x, u2.y), (int)pack_rne(u2.z, u2.w),
                               (int)pack_rne(u3.x, u3.y), (int)pack_rne(u3.z, u3.w) };
    }
    __syncthreads();

    float rt_acc[3][4][2] = {};

    for (int si = 0; si < 24; ++si) {
        const int srow = wave * 24 + si;
        f32x2 af2[8];
        {
            intx4 av0 = *(const intx4*)(a_lds + srow * 36 + quad * 4);
            intx4 av1 = *(const intx4*)(a_lds + srow * 36 + 16 + quad * 4);
#pragma unroll
            for (int j = 0; j < 4; ++j) {
                u32 d0 = (u32)av0[j];
                af2[j] = (f32x2){ __uint_as_float(d0 << 16), __uint_as_float(d0 & 0xffff0000u) };
                u32 d1 = (u32)av1[j];
                af2[4 + j] = (f32x2){ __uint_as_float(d1 << 16), __uint_as_float(d1 & 0xffff0000u) };
            }
        }
        float rs_s[2] = {0.f, 0.f};
#pragma unroll
        for (int tt = 0; tt < 3; ++tt) {
            const u32* bp = b_lds + (tt * 16 + m16) * 36;
            intx4 bv0 = *(const intx4*)(bp + quad * 4);
            intx4 bv1 = *(const intx4*)(bp + 16 + quad * 4);
            Frag w0, w1;
#pragma unroll
            for (int j = 0; j < 4; ++j) {
                u32 d0 = (u32)bv0[j];
                f32x2 p0 = af2[j] * (f32x2){ __uint_as_float(d0 << 16),
                                             __uint_as_float(d0 & 0xffff0000u) };
                w0.i[j] = (int)__builtin_amdgcn_perm(__float_as_uint(p0.y),
                                                     __float_as_uint(p0.x), 0x07060302u);
                u32 d1 = (u32)bv1[j];
                f32x2 p1 = af2[4 + j] * (f32x2){ __uint_as_float(d1 << 16),
                                                 __uint_as_float(d1 & 0xffff0000u) };
                w1.i[j] = (int)__builtin_amdgcn_perm(__float_as_uint(p1.y),
                                                     __float_as_uint(p1.x), 0x07060302u);
            }
#pragma unroll
            for (int jq = 0; jq < 2; ++jq) {
                floatx4 acc = (floatx4){0.f, 0.f, 0.f, 0.f};
                acc = mfma16(w0, cf[jq][0], acc);
                acc = mfma16(w1, cf[jq][1], acc);
#pragma unroll
                for (int rr = 0; rr < 4; ++rr) {
                    float e = fexp2(acc[rr]);
                    rt_acc[tt][rr][jq] += e;
                    rs_s[jq] += e;
                }
            }
        }
#pragma unroll
        for (int jq = 0; jq < 2; ++jq) {
            float v = rs_s[jq];
            v += __shfl_xor(v, 16, 64);
            v += __shfl_xor(v, 32, 64);
            if (lane < 16) rs_lds[srow][jq * 16 + m16] = v;
        }
    }

    __syncthreads();
    for (int w = 0; w < 4; ++w) {
        if (wave == w) {
#pragma unroll
            for (int tt = 0; tt < 3; ++tt)
#pragma unroll
                for (int rr = 0; rr < 4; ++rr) {
                    int t = tt * 16 + quad * 4 + rr;
#pragma unroll
                    for (int jq = 0; jq < 2; ++jq) {
                        if (w == 0) rt_lds[t][jq * 16 + m16] = rt_acc[tt][rr][jq];
                        else        rt_lds[t][jq * 16 + m16] += rt_acc[tt][rr][jq];
                    }
                }
        }
        __syncthreads();
    }
    for (int i = tid; i < 32 * 96; i += 256) {
        int qq = i / 96, ss = i % 96;
        rs_g[((size_t)(tc * 16 + bh) * T_ + q0 + qq) * T_ + s0 + ss] = rs_lds[ss][qq];
    }
    for (int i = tid; i < 32 * 48; i += 256) {
        int qq = i / 48, t2 = i % 48;
        rt_g[((size_t)(sc * 16 + bh) * T_ + q0 + qq) * T_ + t0 + t2] = rt_lds[t2][qq];
    }
}

// ------- zgemm: z[q][d] = ( [rs|rt] @ DE^T ) / Z  per bh; d split across 2 blocks -------
__global__ __launch_bounds__(256) void zgemm(
    const float* __restrict__ rs_g, const float* __restrict__ rt_g,
    const float* __restrict__ proj, u16* __restrict__ zzh, u16* __restrict__ zzl)
{
    __shared__ u16 As[2][64][68];
    __shared__ u16 Bs[32][68];
    __shared__ float zred[64][4];
    __shared__ float Zl[64];
    const int mt = blockIdx.x >> 1, dh2 = blockIdx.x & 1, bh = blockIdx.y;
    const int b = bh >> 2, h = bh & 3;
    const int q0 = mt * 64;
    const int tid = threadIdx.x;
    const int lane = tid & 63, wave = tid >> 6;
    const int m16 = lane & 15, quad = lane >> 4;
    const int wm = (wave >> 1) * 32, wn = (wave & 1) * 16;
    const int r = tid >> 2, c16 = (tid & 3) * 16;

    {
        float zp = 0.f;
        const int j = tid & 3;
#pragma unroll
        for (int tc = 0; tc < 4; ++tc) {
            const float* p = rs_g + ((size_t)(tc * 16 + bh) * T_ + q0 + r) * T_ + j * 48;
#pragma unroll
            for (int s = 0; s < 48; s += 4) {
                float4 v = *(const float4*)(p + s);
                zp += (v.x + v.y) + (v.z + v.w);
            }
        }
        zred[r][j] = zp;
    }
    __syncthreads();
    if (tid < 64)
        Zl[tid] = 1.0f / (zred[tid][0] + zred[tid][1] + zred[tid][2] + zred[tid][3]);

    floatx4 acc[2];
    acc[0] = (floatx4){0.f, 0.f, 0.f, 0.f};
    acc[1] = (floatx4){0.f, 0.f, 0.f, 0.f};

    for (int k0 = 0; k0 < 384; k0 += 64) {
        __syncthreads();
        {
            float g[16];
#pragma unroll
            for (int i = 0; i < 16; ++i) g[i] = 0.f;
            if (k0 < 192) {
#pragma unroll
                for (int tc = 0; tc < 4; ++tc) {
                    const float* p = rs_g + ((size_t)(tc * 16 + bh) * T_ + q0 + r) * T_ + k0 + c16;
#pragma unroll
                    for (int i = 0; i < 16; i += 4) {
                        float4 v = *(const float4*)(p + i);
                        g[i] += v.x; g[i + 1] += v.y; g[i + 2] += v.z; g[i + 3] += v.w;
                    }
                }
            } else {
#pragma unroll
                for (int sc = 0; sc < 2; ++sc) {
                    const float* p = rt_g + ((size_t)(sc * 16 + bh) * T_ + q0 + r) * T_ + (k0 - 192) + c16;
#pragma unroll
                    for (int i = 0; i < 16; i += 4) {
                        float4 v = *(const float4*)(p + i);
                        g[i] += v.x; g[i + 1] += v.y; g[i + 2] += v.z; g[i + 3] += v.w;
                    }
                }
            }
#pragma unroll
            for (int i = 0; i < 16; ++i) {
                u16 hi = bf16_rne(g[i]);
                As[0][r][c16 + i] = hi;
                As[1][r][c16 + i] = bf16_rne(g[i] - bf16f(hi));
            }
        }
        {
            const int colbase = (k0 < 192 ? 768 : 1024) + h * 64 + dh2 * 32;
            const int s0 = (k0 < 192 ? k0 : k0 - 192);
            const int sl = tid >> 2;
            const int d4b = (tid & 3) * 4;
#pragma unroll
            for (int i = 0; i < 2; ++i) {
                int dd = d4b + i * 16;
                float4 v = *(const float4*)(proj + (size_t)(b * T_ + s0 + sl) * 1280 + colbase + dd);
                Bs[dd + 0][sl] = bf16_rne(v.x);
                Bs[dd + 1][sl] = bf16_rne(v.y);
                Bs[dd + 2][sl] = bf16_rne(v.z);
                Bs[dd + 3][sl] = bf16_rne(v.w);
            }
        }
        __syncthreads();
#pragma unroll
        for (int ks = 0; ks < 2; ++ks) {
            const int ko = ks * 32 + quad * 8;
            Frag g0h = ld_frag8(&As[0][wm + m16][ko]);
            Frag g1h = ld_frag8(&As[0][wm + 16 + m16][ko]);
            Frag g0l = ld_frag8(&As[1][wm + m16][ko]);
            Frag g1l = ld_frag8(&As[1][wm + 16 + m16][ko]);
            Frag d0 = ld_frag8(&Bs[wn + m16][ko]);
            acc[0] = mfma16(g0h, d0, acc[0]);
            acc[0] = mfma16(g0l, d0, acc[0]);
            acc[1] = mfma16(g1h, d0, acc[1]);
            acc[1] = mfma16(g1l, d0, acc[1]);
        }
    }
#pragma unroll
    for (int i = 0; i < 2; ++i)
#pragma unroll
        for (int rr = 0; rr < 4; ++rr) {
            int m = wm + i * 16 + quad * 4 + rr;
            int d = dh2 * 32 + wn + m16;
            float zv = acc[i][rr] * Zl[m];
            size_t idx = (size_t)(b * T_ + q0 + m) * 256 + h * 64 + d;
            u16 hi = bf16_rne(zv);
            zzh[idx] = hi;
            zzl[idx] = bf16_rne(zv - bf16f(hi));
        }
}

extern "C" void kernel_launch(void* const* d_in, const int* in_sizes, int n_in,
                              void* d_out, int out_size, void* d_ws, size_t ws_size,
                              hipStream_t stream)
{
    const float* x      = (const float*)d_in[0];
    const float* ln1_g  = (const float*)d_in[1];
    const float* ln1_b  = (const float*)d_in[2];
    const float* Wqkv   = (const float*)d_in[3];
    const float* Wo     = (const float*)d_in[4];
    const float* bo     = (const float*)d_in[5];
    const float* ln2_g  = (const float*)d_in[6];
    const float* ln2_b  = (const float*)d_in[7];
    const float* Wabcde = (const float*)d_in[8];
    const float* babcde = (const float*)d_in[9];
    const float* Wp     = (const float*)d_in[10];
    const float* bp     = (const float*)d_in[11];
    float* out = (float*)d_out;

    // ---- workspace layout (f32 units), total 6,684,672 f = 25.5 MiB ----
    float* ws   = (float*)d_ws;
    float* proj = ws;                              // 983,040 f (alive through zgemm)
    u16* wofh   = (u16*)(proj + 983040);           // 512*768 hi/lo = 393,216 f
    u16* wofl   = wofh + 393216;
    u16* aoh    = (u16*)(ws + 1376256);            // 768*512 hi/lo = 393,216 f
    u16* aol    = aoh + 393216;
    u16* zh     = (u16*)(ws + 1769472);            // z hi/lo = 196,608 f
    u16* zl     = zh + 196608;
    float* rs   = ws + 1966080;                    // 4 tc-partials: 2,359,296 f
    float* rt   = rs + 2359296;                    // 2 sc-partials used (region 2,359,296 f)
    // aliases (disjoint lifetimes):
    float* qkv = rs;                               // dead before rs written
    u16* x1h = (u16*)(rs + 1179648);               // x bufs in rs tail
    u16* x1l = x1h + 393216;
    u16* x2h = x1l + 393216;
    u16* x2l = x2h + 393216;
    u16* wqh = (u16*)rt;                           // Wqkv^T (hi only) in rt head
    u16* wah = wqh + 786432;                       // Wabcde^T (hi only) after it
    // both dead before rt written by tritt

    prep_kernel<<<1216, 256, 0, stream>>>(x, ln1_g, ln1_b, ln2_g, ln2_b,
                                          x1h, x1l, x2h, x2l,
                                          Wqkv, wqh, Wabcde, wah,
                                          Wo, Wp, wofh, wofl);
    gemm_dual<<<dim3(44, 12), 256, 0, stream>>>(x1h, x1l, wqh, x2h, x2l, wah,
                                                babcde, qkv, proj);
    attn_mfma<<<dim3(3, AH, B_), 256, 0, stream>>>(qkv, aoh, aol);
    tritt_score_mfma<<<dim3(48, CH, B_), 256, 0, stream>>>(proj, rs, rt);
    zgemm<<<dim3(6, 16), 256, 0, stream>>>(rs, rt, proj, zh, zl);
    gemm_epilogue<<<dim3(8, 24), 256, 0, stream>>>(aoh, aol, zh, zl, wofh, wofl, bo, bp, out);
}